// Round 16
// baseline (2071.850 us; speedup 1.0000x reference)
//
#include <hip/hip_runtime.h>

// Wave-level LDS ordering fence for the few remaining LDS phase transitions.
#define FENCE() asm volatile("s_waitcnt lgkmcnt(0)" ::: "memory")

typedef float v2f   __attribute__((ext_vector_type(2)));
typedef float f32x4 __attribute__((ext_vector_type(4)));

__device__ __forceinline__ float fshfl_xor(float v, int m) { return __shfl_xor(v, m, 64); }
__device__ __forceinline__ float fsqrt(float x) { return __builtin_amdgcn_sqrtf(x); }
__device__ __forceinline__ float frcp (float x) { return __builtin_amdgcn_rcpf(x); }
__device__ __forceinline__ float frsq (float x) { return __builtin_amdgcn_rsqf(x); }
__device__ __forceinline__ v2f   fma2(v2f a, v2f b, v2f c)       { return __builtin_elementwise_fma(a, b, c); }
__device__ __forceinline__ f32x4 fma4(f32x4 a, f32x4 b, f32x4 c) { return __builtin_elementwise_fma(a, b, c); }

// One block = 256 threads = 4 waves, one 32x32 SPD matrix per wave.
// r16 = r15 + launch_bounds(256,8), single change (controlled A/B).
// r15 landed the clean build (WRITE_SIZE 2304, VGPR 56) but occupancy parked
// at 46% -- with no waves-per-EU metadata the toolchain defaults the
// occupancy target to ~4/EU. r15's natural VGPR usage (56) now FITS the
// bounds-8 budget (64) that r12's fatter code overflowed, so bounds-8 should
// compile clean AND lift the cap to 8 waves/EU (measured: arg tracks
// occupancy 8->87%, 6->67%, 4->46%). At 46% occ we idle 42% of VALU on the
// serial shuffle-chain latency (18 DS-pipe ops/round); 2x waves hides it.
// Spill tripwire: WRITE_SIZE must stay ~2.3MB, else revert to no-arg.
// LDS: 4*1152*4 = 18432 B/block.
#define PT_S 34
__global__ __launch_bounds__(256, 8) void spd_fused(
    const float* __restrict__ xg,
    const float* __restrict__ w1g,
    const float* __restrict__ w2g,
    const float* __restrict__ w3g,
    const float* __restrict__ fcg,
    float* __restrict__ outg,
    int B)
{
  __shared__ float slot[4][1152];

  const int tid  = threadIdx.x;
  const int wid  = tid >> 6;
  const int lane = tid & 63;

  float* Cc = slot[wid];          // x (stride 32) -> M1 cols (stride 36) -> Qb/J scratch
  float* Pt = slot[wid] + 576;    // Ps transposed [16][PT_S], in dead M1 space

  const long b = (long)blockIdx.x * 4 + wid;
  if (b >= B) return;

  // ---------------- load x -> Cc row-major [32][32] (stride 32)
  {
    const f32x4* xv = (const f32x4*)(xg + (size_t)b * 1024);
    f32x4* c4 = (f32x4*)Cc;
    #pragma unroll
    for (int jj = 0; jj < 4; ++jj) {
      int i4 = lane + 64 * jj;
      c4[i4] = xv[i4];
    }
  }
  FENCE();

  const int j = lane & 31;
  const int h = lane >> 5;

  // ---------------- Tmat = x * w1 in registers (packed). T2[e] = rows
  // {16h+2e, +1} of column j. Uses x symmetry: read x rows as f32x4.
  // (c-loop unroll 4 is safe: T2 subscripts are literal constants.)
  v2f T2[8];
  {
    #pragma unroll
    for (int e = 0; e < 8; ++e) T2[e] = (v2f){0.f, 0.f};
    const f32x4* c4 = (const f32x4*)Cc;
    #pragma unroll 4
    for (int c = 0; c < 32; ++c) {
      float wv = w1g[c * 32 + j];
      v2f wv2 = {wv, wv};
      f32x4 x0 = c4[c * 8 + h * 4 + 0];
      f32x4 x1 = c4[c * 8 + h * 4 + 1];
      f32x4 x2 = c4[c * 8 + h * 4 + 2];
      f32x4 x3 = c4[c * 8 + h * 4 + 3];
      T2[0] = fma2(x0.lo, wv2, T2[0]); T2[1] = fma2(x0.hi, wv2, T2[1]);
      T2[2] = fma2(x1.lo, wv2, T2[2]); T2[3] = fma2(x1.hi, wv2, T2[3]);
      T2[4] = fma2(x2.lo, wv2, T2[4]); T2[5] = fma2(x2.hi, wv2, T2[5]);
      T2[6] = fma2(x3.lo, wv2, T2[6]); T2[7] = fma2(x3.hi, wv2, T2[7]);
    }
  }
  FENCE();   // all x reads complete before M1 overwrites Cc

  // ---------------- M1 = w1^T * Tmat -> Cc linear column-major, stride 36.
  // (e-loop FULL unroll: T2[e>>1][e&1] must stay compile-time.)
  {
    const f32x4* w14 = (const f32x4*)w1g;   // row r = w14[r*8 + 0..7]
    #pragma unroll
    for (int ih2 = 0; ih2 < 4; ++ih2) {     // output rows 8*ih2 .. 8*ih2+7
      f32x4 A = {0.f, 0.f, 0.f, 0.f};
      f32x4 Bv = {0.f, 0.f, 0.f, 0.f};
      #pragma unroll
      for (int e = 0; e < 16; ++e) {
        int r = 16 * h + e;
        float tv = T2[e >> 1][e & 1];
        f32x4 tv4 = {tv, tv, tv, tv};
        A  = fma4(w14[r * 8 + ih2 * 2],     tv4, A);
        Bv = fma4(w14[r * 8 + ih2 * 2 + 1], tv4, Bv);
      }
      A.x += fshfl_xor(A.x, 32);  A.y += fshfl_xor(A.y, 32);
      A.z += fshfl_xor(A.z, 32);  A.w += fshfl_xor(A.w, 32);
      Bv.x += fshfl_xor(Bv.x, 32); Bv.y += fshfl_xor(Bv.y, 32);
      Bv.z += fshfl_xor(Bv.z, 32); Bv.w += fshfl_xor(Bv.w, 32);
      if (h == (ih2 & 1)) {
        *(f32x4*)(Cc + j * 36 + ih2 * 8)     = A;
        *(f32x4*)(Cc + j * 36 + ih2 * 8 + 4) = Bv;
      }
    }
  }
  FENCE();

  // ---------------- load own column half into v2f registers (one-time)
  v2f v1[8];
  {
    const float* bp = Cc + j * 36 + (h << 4);
    f32x4 q0 = *(const f32x4*)(bp);
    f32x4 q1 = *(const f32x4*)(bp + 4);
    f32x4 q2 = *(const f32x4*)(bp + 8);
    f32x4 q3 = *(const f32x4*)(bp + 12);
    v1[0] = q0.lo; v1[1] = q0.hi; v1[2] = q1.lo; v1[3] = q1.hi;
    v1[4] = q2.lo; v1[5] = q2.hi; v1[6] = q3.lo; v1[7] = q3.hi;
  }

  // ---------------- one-sided Jacobi, n=32, register-resident, XOR
  // tournament, incremental norms (refreshed each sweep).
  {
    #pragma unroll 1
    for (int sweep = 0; sweep < 8; ++sweep) {
      // fresh own-norm (kills incremental drift)
      v2f s2n = {0.f, 0.f};
      #pragma unroll
      for (int i = 0; i < 8; ++i) s2n = fma2(v1[i], v1[i], s2n);
      float sn = s2n.x + s2n.y;
      sn += fshfl_xor(sn, 32);

      float offmax = 0.f;
      #pragma unroll 1
      for (int mask = 1; mask < 32; ++mask) {
        const int m = j ^ mask;
        v2f uu[8];
        #pragma unroll
        for (int i = 0; i < 8; ++i) {
          uu[i].x = fshfl_xor(v1[i].x, mask);
          uu[i].y = fshfl_xor(v1[i].y, mask);
        }
        float sb_o = fshfl_xor(sn, mask);    // partner's maintained norm
        v2f sgv = {0.f, 0.f};
        #pragma unroll
        for (int i = 0; i < 8; ++i) sgv = fma2(v1[i], uu[i], sgv);
        float sg = sgv.x + sgv.y;
        sg += fshfl_xor(sg, 32);
        const bool isp = j < m;
        float nA = isp ? sn : sb_o;
        float nB = isp ? sb_o : sn;
        float rel = sg * sg * frcp(fmaxf(nA * nB, 1e-30f));
        offmax = fmaxf(offmax, rel);
        if (rel > 1e-13f) {
          float uc = 0.5f * (nB - nA);
          float R  = fsqrt(uc * uc + sg * sg);
          float t  = sg * frcp(uc + ((uc >= 0.f) ? R : -R));
          float ct = frsq(1.f + t * t);
          float st = ct * t;
          float s  = isp ? -st : st;
          v2f ct2 = {ct, ct}, sv2 = {s, s};
          #pragma unroll
          for (int i = 0; i < 8; ++i)
            v1[i] = fma2(uu[i], sv2, v1[i] * ct2);
          // 2x2 Gram eigenvalue identity: a' = nA - t*sg, b' = nB + t*sg
          sn = fmaxf(isp ? (nA - t * sg) : (nB + t * sg), 0.f);
        }
      }
      #pragma unroll
      for (int mm = 1; mm <= 32; mm <<= 1) offmax = fmaxf(offmax, fshfl_xor(offmax, mm));
      if (offmax < 1e-11f) break;
    }
  }

  // ---------------- lambda_1 + ReEig + Ps = sqrt(clamp(lam1))*v1hat^T w2,
  // all from registers (fresh norm); Pt[16][PT_S] transposed (conflict-free).
  // Two statically-unrolled halves with a sched_barrier between: caps the
  // load-hoisting spike (16 in-flight w2 f32x4 = 64 VGPRs); this is what
  // brought natural VGPR usage to 56 in r15.
  {
    v2f ssv = {0.f, 0.f};
    #pragma unroll
    for (int i = 0; i < 8; ++i) ssv = fma2(v1[i], v1[i], ssv);
    float ss = ssv.x + ssv.y;
    ss += fshfl_xor(ss, 32);
    float lam = fsqrt(ss);
    float sc1 = (lam > 0.f) ? (fsqrt(fmaxf(lam, 1e-4f)) * frcp(lam)) : 0.f;
    f32x4 acc0 = {0.f,0.f,0.f,0.f}, acc1 = acc0, acc2 = acc0, acc3 = acc0;
    #pragma unroll
    for (int t = 0; t < 4; ++t) {
      int rr = (h << 4) + 2 * t;
      const f32x4* wr0 = (const f32x4*)(w2g + rr * 16);
      const f32x4* wr1 = (const f32x4*)(w2g + (rr + 1) * 16);
      float vx = v1[t].x, vy = v1[t].y;
      f32x4 vx4 = {vx, vx, vx, vx};
      f32x4 vy4 = {vy, vy, vy, vy};
      acc0 = fma4(wr0[0], vx4, acc0); acc1 = fma4(wr0[1], vx4, acc1);
      acc2 = fma4(wr0[2], vx4, acc2); acc3 = fma4(wr0[3], vx4, acc3);
      acc0 = fma4(wr1[0], vy4, acc0); acc1 = fma4(wr1[1], vy4, acc1);
      acc2 = fma4(wr1[2], vy4, acc2); acc3 = fma4(wr1[3], vy4, acc3);
    }
    __builtin_amdgcn_sched_barrier(0);   // don't hoist 2nd-half loads above
    #pragma unroll
    for (int t = 4; t < 8; ++t) {
      int rr = (h << 4) + 2 * t;
      const f32x4* wr0 = (const f32x4*)(w2g + rr * 16);
      const f32x4* wr1 = (const f32x4*)(w2g + (rr + 1) * 16);
      float vx = v1[t].x, vy = v1[t].y;
      f32x4 vx4 = {vx, vx, vx, vx};
      f32x4 vy4 = {vy, vy, vy, vy};
      acc0 = fma4(wr0[0], vx4, acc0); acc1 = fma4(wr0[1], vx4, acc1);
      acc2 = fma4(wr0[2], vx4, acc2); acc3 = fma4(wr0[3], vx4, acc3);
      acc0 = fma4(wr1[0], vy4, acc0); acc1 = fma4(wr1[1], vy4, acc1);
      acc2 = fma4(wr1[2], vy4, acc2); acc3 = fma4(wr1[3], vy4, acc3);
    }
    acc0.x = (acc0.x + fshfl_xor(acc0.x, 32)) * sc1;
    acc0.y = (acc0.y + fshfl_xor(acc0.y, 32)) * sc1;
    acc0.z = (acc0.z + fshfl_xor(acc0.z, 32)) * sc1;
    acc0.w = (acc0.w + fshfl_xor(acc0.w, 32)) * sc1;
    acc1.x = (acc1.x + fshfl_xor(acc1.x, 32)) * sc1;
    acc1.y = (acc1.y + fshfl_xor(acc1.y, 32)) * sc1;
    acc1.z = (acc1.z + fshfl_xor(acc1.z, 32)) * sc1;
    acc1.w = (acc1.w + fshfl_xor(acc1.w, 32)) * sc1;
    acc2.x = (acc2.x + fshfl_xor(acc2.x, 32)) * sc1;
    acc2.y = (acc2.y + fshfl_xor(acc2.y, 32)) * sc1;
    acc2.z = (acc2.z + fshfl_xor(acc2.z, 32)) * sc1;
    acc2.w = (acc2.w + fshfl_xor(acc2.w, 32)) * sc1;
    acc3.x = (acc3.x + fshfl_xor(acc3.x, 32)) * sc1;
    acc3.y = (acc3.y + fshfl_xor(acc3.y, 32)) * sc1;
    acc3.z = (acc3.z + fshfl_xor(acc3.z, 32)) * sc1;
    acc3.w = (acc3.w + fshfl_xor(acc3.w, 32)) * sc1;
    // lane (j,h) stores Ps[j][8h..8h+7]: h=0 -> acc0/acc1, h=1 -> acc2/acc3
    f32x4 lo = h ? acc2 : acc0;
    f32x4 hi = h ? acc3 : acc1;
    const int jb8 = h << 3;
    Pt[(jb8 + 0) * PT_S + j] = lo.x;
    Pt[(jb8 + 1) * PT_S + j] = lo.y;
    Pt[(jb8 + 2) * PT_S + j] = lo.z;
    Pt[(jb8 + 3) * PT_S + j] = lo.w;
    Pt[(jb8 + 4) * PT_S + j] = hi.x;
    Pt[(jb8 + 5) * PT_S + j] = hi.y;
    Pt[(jb8 + 6) * PT_S + j] = hi.z;
    Pt[(jb8 + 7) * PT_S + j] = hi.w;
  }
  FENCE();

  // ---------------- M2 = Ps^T Ps directly into stage-2 registers.
  // lane = c2 + 16*h4 owns rows 4h4..4h4+3 of M2 column c2.
  // (kk-loop unroll 2 safe: only LDS pointers use kk.)
  const int c2 = lane & 15;
  const int h4 = lane >> 4;
  f32x4 v2r;
  {
    v2f a0 = {0.f,0.f}, a1 = {0.f,0.f}, a2 = {0.f,0.f}, a3 = {0.f,0.f};
    #pragma unroll 2
    for (int kk = 0; kk < 32; kk += 4) {
      f32x4 aa = *(const f32x4*)(Pt + c2 * PT_S + kk);
      f32x4 b0 = *(const f32x4*)(Pt + (4 * h4 + 0) * PT_S + kk);
      f32x4 b1 = *(const f32x4*)(Pt + (4 * h4 + 1) * PT_S + kk);
      f32x4 b2 = *(const f32x4*)(Pt + (4 * h4 + 2) * PT_S + kk);
      f32x4 b3 = *(const f32x4*)(Pt + (4 * h4 + 3) * PT_S + kk);
      a0 = fma2(aa.lo, b0.lo, a0); a0 = fma2(aa.hi, b0.hi, a0);
      a1 = fma2(aa.lo, b1.lo, a1); a1 = fma2(aa.hi, b1.hi, a1);
      a2 = fma2(aa.lo, b2.lo, a2); a2 = fma2(aa.hi, b2.hi, a2);
      a3 = fma2(aa.lo, b3.lo, a3); a3 = fma2(aa.hi, b3.hi, a3);
    }
    v2r.x = a0.x + a0.y;
    v2r.y = a1.x + a1.y;
    v2r.z = a2.x + a2.y;
    v2r.w = a3.x + a3.y;
  }

  // ---------------- one-sided Jacobi, n=16, register-resident, XOR
  // tournament, incremental norms.
  {
    #pragma unroll 1
    for (int sweep = 0; sweep < 6; ++sweep) {
      v2f sp = fma2(v2r.hi, v2r.hi, v2r.lo * v2r.lo);
      float sn2 = sp.x + sp.y;
      sn2 += fshfl_xor(sn2, 16);
      sn2 += fshfl_xor(sn2, 32);
      float offmax = 0.f;
      #pragma unroll 1
      for (int mask = 1; mask < 16; ++mask) {
        const int m = c2 ^ mask;
        float u0 = fshfl_xor(v2r.x, mask);
        float u1 = fshfl_xor(v2r.y, mask);
        float u2 = fshfl_xor(v2r.z, mask);
        float u3 = fshfl_xor(v2r.w, mask);
        float sb_o = fshfl_xor(sn2, mask);
        v2f ua = {u0, u1}, ub = {u2, u3};
        v2f sgv = fma2(v2r.hi, ub, v2r.lo * ua);
        float sg = sgv.x + sgv.y;
        sg += fshfl_xor(sg, 16);
        sg += fshfl_xor(sg, 32);
        const bool isp = c2 < m;
        float nA = isp ? sn2 : sb_o;
        float nB = isp ? sb_o : sn2;
        float rel = sg * sg * frcp(fmaxf(nA * nB, 1e-30f));
        offmax = fmaxf(offmax, rel);
        if (rel > 1e-13f) {
          float uc = 0.5f * (nB - nA);
          float R  = fsqrt(uc * uc + sg * sg);
          float t  = sg * frcp(uc + ((uc >= 0.f) ? R : -R));
          float ct = frsq(1.f + t * t);
          float st = ct * t;
          float s  = isp ? -st : st;
          f32x4 ct4 = {ct, ct, ct, ct};
          f32x4 s4  = {s, s, s, s};
          f32x4 uu4 = {u0, u1, u2, u3};
          v2r = fma4(uu4, s4, v2r * ct4);
          sn2 = fmaxf(isp ? (nA - t * sg) : (nB + t * sg), 0.f);
        }
      }
      #pragma unroll
      for (int mm = 1; mm <= 32; mm <<= 1) offmax = fmaxf(offmax, fshfl_xor(offmax, mm));
      if (offmax < 1e-11f) break;
    }
  }

  // ---------------- Qb row c2 = (V2^T w3)[c2][:] * sqrt(clamp(lam2)) from regs
  {
    f32x4 qq = {0.f, 0.f, 0.f, 0.f};
    f32x4 w0 = *(const f32x4*)(w3g + (4 * h4 + 0) * 4);
    f32x4 w1r = *(const f32x4*)(w3g + (4 * h4 + 1) * 4);
    f32x4 w2r = *(const f32x4*)(w3g + (4 * h4 + 2) * 4);
    f32x4 w3r = *(const f32x4*)(w3g + (4 * h4 + 3) * 4);
    f32x4 vv0 = {v2r.x, v2r.x, v2r.x, v2r.x};
    f32x4 vv1 = {v2r.y, v2r.y, v2r.y, v2r.y};
    f32x4 vv2 = {v2r.z, v2r.z, v2r.z, v2r.z};
    f32x4 vv3 = {v2r.w, v2r.w, v2r.w, v2r.w};
    qq = fma4(w0, vv0, qq); qq = fma4(w1r, vv1, qq);
    qq = fma4(w2r, vv2, qq); qq = fma4(w3r, vv3, qq);
    v2f sp = fma2(v2r.hi, v2r.hi, v2r.lo * v2r.lo);
    float ssp = sp.x + sp.y;
    float q0 = qq.x, q1 = qq.y, q2 = qq.z, q3 = qq.w;
    q0 += fshfl_xor(q0, 16); q0 += fshfl_xor(q0, 32);
    q1 += fshfl_xor(q1, 16); q1 += fshfl_xor(q1, 32);
    q2 += fshfl_xor(q2, 16); q2 += fshfl_xor(q2, 32);
    q3 += fshfl_xor(q3, 16); q3 += fshfl_xor(q3, 32);
    ssp += fshfl_xor(ssp, 16); ssp += fshfl_xor(ssp, 32);
    float lam = fsqrt(ssp);
    float scl = (lam > 0.f) ? (frcp(lam) * fsqrt(fmaxf(lam, 1e-4f))) : 0.f;
    if (h4 == 0)
      *(f32x4*)(Cc + c2 * 4) = (f32x4){q0 * scl, q1 * scl, q2 * scl, q3 * scl};
  }
  FENCE();

  // ---------------- stage 3: one-sided Jacobi ON THE 16x4 FACTOR, with
  // accumulated rotations J (eigenvectors of M3 = Q^T Q). 5 sweeps.
  float qv = Cc[lane];            // Qb[kq][jq], kq*4+jq == lane
  const int kq = lane >> 2;
  const int jq = lane & 3;
  float jv = (kq == jq) ? 1.f : 0.f;
  {
    #define ROT3(P_, Q_) do {                                             \
      float w_ = fshfl_xor(qv, (P_) ^ (Q_));                              \
      float s1 = qv * qv, s2 = w_ * w_, s3 = qv * w_;                     \
      s1 += fshfl_xor(s1, 4);  s2 += fshfl_xor(s2, 4);  s3 += fshfl_xor(s3, 4);  \
      s1 += fshfl_xor(s1, 8);  s2 += fshfl_xor(s2, 8);  s3 += fshfl_xor(s3, 8);  \
      s1 += fshfl_xor(s1, 16); s2 += fshfl_xor(s2, 16); s3 += fshfl_xor(s3, 16); \
      s1 += fshfl_xor(s1, 32); s2 += fshfl_xor(s2, 32); s3 += fshfl_xor(s3, 32); \
      bool isp = (jq == (P_)), isq = (jq == (Q_));                        \
      float sa = isp ? s1 : s2;                                           \
      float sb = isp ? s2 : s1;                                           \
      float u_ = 0.5f * (sb - sa);                                        \
      float R_ = fsqrt(u_ * u_ + s3 * s3);                                \
      float dn_ = u_ + copysignf(fmaxf(R_, 1e-30f), u_);                  \
      float t_ = s3 * frcp(dn_);                                          \
      float ct = frsq(1.f + t_ * t_);                                     \
      float st = ct * t_;                                                 \
      float wj_ = fshfl_xor(jv, (P_) ^ (Q_));                             \
      float nv  = isp ? (ct * qv - st * w_)  : (st * w_  + ct * qv);      \
      float nvj = isp ? (ct * jv - st * wj_) : (st * wj_ + ct * jv);      \
      if (isp | isq) { qv = nv; jv = nvj; }                               \
    } while (0)

    #pragma unroll 1
    for (int sweep = 0; sweep < 5; ++sweep) {
      ROT3(0,1); ROT3(2,3); ROT3(0,2); ROT3(1,3); ROT3(0,3); ROT3(1,2);
    }
    #undef ROT3
  }

  // ---------------- lambda_3 = ||col||^2, LogEig via J, FC, log_softmax
  {
    float ss = qv * qv;
    ss += fshfl_xor(ss, 4); ss += fshfl_xor(ss, 8);
    ss += fshfl_xor(ss, 16); ss += fshfl_xor(ss, 32);
    float lwv = logf(fmaxf(ss, 1e-10f));       // log eigenvalue of column jq
    if (kq < 4)  Cc[64 + kq * 4 + jq] = jv;    // J, row-major 4x4
    if (kq == 0) Cc[80 + jq] = lwv;            // lanes 0..3: per-column loglam
    FENCE();

    float f = 0.f;
    if (lane < 16) {
      int i3 = lane >> 2, j3 = lane & 3;
      #pragma unroll
      for (int c = 0; c < 4; ++c)
        f += Cc[80 + c] * Cc[64 + i3 * 4 + c] * Cc[64 + j3 * 4 + c];
    }
    float t0 = 0.f, t1 = 0.f;
    if (lane < 16) { t0 = f * fcg[2 * lane]; t1 = f * fcg[2 * lane + 1]; }
    t0 += fshfl_xor(t0, 1); t1 += fshfl_xor(t1, 1);
    t0 += fshfl_xor(t0, 2); t1 += fshfl_xor(t1, 2);
    t0 += fshfl_xor(t0, 4); t1 += fshfl_xor(t1, 4);
    t0 += fshfl_xor(t0, 8); t1 += fshfl_xor(t1, 8);
    float mx  = fmaxf(t0, t1);
    float lse = mx + logf(expf(t0 - mx) + expf(t1 - mx));

    float* outFeat = outg + (size_t)B * 2;
    if (lane < 16) outFeat[(size_t)b * 16 + lane] = f;
    if (lane < 2)  outg[(size_t)b * 2 + lane] = (lane == 0 ? t0 : t1) - lse;
  }
}

extern "C" void kernel_launch(void* const* d_in, const int* in_sizes, int n_in,
                              void* d_out, int out_size, void* d_ws, size_t ws_size,
                              hipStream_t stream) {
  const float* x  = (const float*)d_in[0];
  const float* w1 = (const float*)d_in[1];
  const float* w2 = (const float*)d_in[2];
  const float* w3 = (const float*)d_in[3];
  const float* fc = (const float*)d_in[4];
  float* out = (float*)d_out;
  int B = in_sizes[0] / 1024;
  int grid = (B + 3) / 4;
  hipLaunchKernelGGL(spd_fused, dim3(grid), dim3(256), 0, stream,
                     x, w1, w2, w3, fc, out, B);
}

// Round 17
// 2067.052 us; speedup vs baseline: 1.0023x; 1.0023x over previous
//
#include <hip/hip_runtime.h>

// Wave-level LDS ordering fence for the few remaining LDS phase transitions.
#define FENCE() asm volatile("s_waitcnt lgkmcnt(0)" ::: "memory")

typedef float v2f   __attribute__((ext_vector_type(2)));
typedef float f32x4 __attribute__((ext_vector_type(4)));

__device__ __forceinline__ float fshfl_xor(float v, int m) { return __shfl_xor(v, m, 64); }
__device__ __forceinline__ float fsqrt(float x) { return __builtin_amdgcn_sqrtf(x); }
__device__ __forceinline__ float frcp (float x) { return __builtin_amdgcn_rcpf(x); }
__device__ __forceinline__ float frsq (float x) { return __builtin_amdgcn_rsqf(x); }
__device__ __forceinline__ v2f   fma2(v2f a, v2f b, v2f c)       { return __builtin_elementwise_fma(a, b, c); }
__device__ __forceinline__ f32x4 fma4(f32x4 a, f32x4 b, f32x4 c) { return __builtin_elementwise_fma(a, b, c); }

// One block = 256 threads = 4 waves, one 32x32 SPD matrix per wave.
// r17 = r15 source + launch_bounds(256,6), single change (controlled A/B).
// Experiment grid: fat+b6=spill/67%/2058, fat+b8=spill/87%/2078,
// lean+none=CLEAN/46%/2030, lean+b8=spill/87%/2072 (r16: budget-64 panics
// even at natural usage 56 -- pre-RA scheduling peaks force spill).
// Untested cell: LEAN + bounds-6 (budget ~85 > lean peak demand ~70).
// If clean: best of both (clean code at the 67% occupancy tier).
// Spill tripwire: WRITE_SIZE must read ~2.3MB, else r15 is final.
// LDS: 4*1152*4 = 18432 B/block.
#define PT_S 34
__global__ __launch_bounds__(256, 6) void spd_fused(
    const float* __restrict__ xg,
    const float* __restrict__ w1g,
    const float* __restrict__ w2g,
    const float* __restrict__ w3g,
    const float* __restrict__ fcg,
    float* __restrict__ outg,
    int B)
{
  __shared__ float slot[4][1152];

  const int tid  = threadIdx.x;
  const int wid  = tid >> 6;
  const int lane = tid & 63;

  float* Cc = slot[wid];          // x (stride 32) -> M1 cols (stride 36) -> Qb/J scratch
  float* Pt = slot[wid] + 576;    // Ps transposed [16][PT_S], in dead M1 space

  const long b = (long)blockIdx.x * 4 + wid;
  if (b >= B) return;

  // ---------------- load x -> Cc row-major [32][32] (stride 32)
  {
    const f32x4* xv = (const f32x4*)(xg + (size_t)b * 1024);
    f32x4* c4 = (f32x4*)Cc;
    #pragma unroll
    for (int jj = 0; jj < 4; ++jj) {
      int i4 = lane + 64 * jj;
      c4[i4] = xv[i4];
    }
  }
  FENCE();

  const int j = lane & 31;
  const int h = lane >> 5;

  // ---------------- Tmat = x * w1 in registers (packed). T2[e] = rows
  // {16h+2e, +1} of column j. Uses x symmetry: read x rows as f32x4.
  // (c-loop unroll 4 is safe: T2 subscripts are literal constants.)
  v2f T2[8];
  {
    #pragma unroll
    for (int e = 0; e < 8; ++e) T2[e] = (v2f){0.f, 0.f};
    const f32x4* c4 = (const f32x4*)Cc;
    #pragma unroll 4
    for (int c = 0; c < 32; ++c) {
      float wv = w1g[c * 32 + j];
      v2f wv2 = {wv, wv};
      f32x4 x0 = c4[c * 8 + h * 4 + 0];
      f32x4 x1 = c4[c * 8 + h * 4 + 1];
      f32x4 x2 = c4[c * 8 + h * 4 + 2];
      f32x4 x3 = c4[c * 8 + h * 4 + 3];
      T2[0] = fma2(x0.lo, wv2, T2[0]); T2[1] = fma2(x0.hi, wv2, T2[1]);
      T2[2] = fma2(x1.lo, wv2, T2[2]); T2[3] = fma2(x1.hi, wv2, T2[3]);
      T2[4] = fma2(x2.lo, wv2, T2[4]); T2[5] = fma2(x2.hi, wv2, T2[5]);
      T2[6] = fma2(x3.lo, wv2, T2[6]); T2[7] = fma2(x3.hi, wv2, T2[7]);
    }
  }
  FENCE();   // all x reads complete before M1 overwrites Cc

  // ---------------- M1 = w1^T * Tmat -> Cc linear column-major, stride 36.
  // (e-loop FULL unroll: T2[e>>1][e&1] must stay compile-time.)
  {
    const f32x4* w14 = (const f32x4*)w1g;   // row r = w14[r*8 + 0..7]
    #pragma unroll
    for (int ih2 = 0; ih2 < 4; ++ih2) {     // output rows 8*ih2 .. 8*ih2+7
      f32x4 A = {0.f, 0.f, 0.f, 0.f};
      f32x4 Bv = {0.f, 0.f, 0.f, 0.f};
      #pragma unroll
      for (int e = 0; e < 16; ++e) {
        int r = 16 * h + e;
        float tv = T2[e >> 1][e & 1];
        f32x4 tv4 = {tv, tv, tv, tv};
        A  = fma4(w14[r * 8 + ih2 * 2],     tv4, A);
        Bv = fma4(w14[r * 8 + ih2 * 2 + 1], tv4, Bv);
      }
      A.x += fshfl_xor(A.x, 32);  A.y += fshfl_xor(A.y, 32);
      A.z += fshfl_xor(A.z, 32);  A.w += fshfl_xor(A.w, 32);
      Bv.x += fshfl_xor(Bv.x, 32); Bv.y += fshfl_xor(Bv.y, 32);
      Bv.z += fshfl_xor(Bv.z, 32); Bv.w += fshfl_xor(Bv.w, 32);
      if (h == (ih2 & 1)) {
        *(f32x4*)(Cc + j * 36 + ih2 * 8)     = A;
        *(f32x4*)(Cc + j * 36 + ih2 * 8 + 4) = Bv;
      }
    }
  }
  FENCE();

  // ---------------- load own column half into v2f registers (one-time)
  v2f v1[8];
  {
    const float* bp = Cc + j * 36 + (h << 4);
    f32x4 q0 = *(const f32x4*)(bp);
    f32x4 q1 = *(const f32x4*)(bp + 4);
    f32x4 q2 = *(const f32x4*)(bp + 8);
    f32x4 q3 = *(const f32x4*)(bp + 12);
    v1[0] = q0.lo; v1[1] = q0.hi; v1[2] = q1.lo; v1[3] = q1.hi;
    v1[4] = q2.lo; v1[5] = q2.hi; v1[6] = q3.lo; v1[7] = q3.hi;
  }

  // ---------------- one-sided Jacobi, n=32, register-resident, XOR
  // tournament, incremental norms (refreshed each sweep).
  {
    #pragma unroll 1
    for (int sweep = 0; sweep < 8; ++sweep) {
      // fresh own-norm (kills incremental drift)
      v2f s2n = {0.f, 0.f};
      #pragma unroll
      for (int i = 0; i < 8; ++i) s2n = fma2(v1[i], v1[i], s2n);
      float sn = s2n.x + s2n.y;
      sn += fshfl_xor(sn, 32);

      float offmax = 0.f;
      #pragma unroll 1
      for (int mask = 1; mask < 32; ++mask) {
        const int m = j ^ mask;
        v2f uu[8];
        #pragma unroll
        for (int i = 0; i < 8; ++i) {
          uu[i].x = fshfl_xor(v1[i].x, mask);
          uu[i].y = fshfl_xor(v1[i].y, mask);
        }
        float sb_o = fshfl_xor(sn, mask);    // partner's maintained norm
        v2f sgv = {0.f, 0.f};
        #pragma unroll
        for (int i = 0; i < 8; ++i) sgv = fma2(v1[i], uu[i], sgv);
        float sg = sgv.x + sgv.y;
        sg += fshfl_xor(sg, 32);
        const bool isp = j < m;
        float nA = isp ? sn : sb_o;
        float nB = isp ? sb_o : sn;
        float rel = sg * sg * frcp(fmaxf(nA * nB, 1e-30f));
        offmax = fmaxf(offmax, rel);
        if (rel > 1e-13f) {
          float uc = 0.5f * (nB - nA);
          float R  = fsqrt(uc * uc + sg * sg);
          float t  = sg * frcp(uc + ((uc >= 0.f) ? R : -R));
          float ct = frsq(1.f + t * t);
          float st = ct * t;
          float s  = isp ? -st : st;
          v2f ct2 = {ct, ct}, sv2 = {s, s};
          #pragma unroll
          for (int i = 0; i < 8; ++i)
            v1[i] = fma2(uu[i], sv2, v1[i] * ct2);
          // 2x2 Gram eigenvalue identity: a' = nA - t*sg, b' = nB + t*sg
          sn = fmaxf(isp ? (nA - t * sg) : (nB + t * sg), 0.f);
        }
      }
      #pragma unroll
      for (int mm = 1; mm <= 32; mm <<= 1) offmax = fmaxf(offmax, fshfl_xor(offmax, mm));
      if (offmax < 1e-11f) break;
    }
  }

  // ---------------- lambda_1 + ReEig + Ps = sqrt(clamp(lam1))*v1hat^T w2,
  // all from registers (fresh norm); Pt[16][PT_S] transposed (conflict-free).
  // Two statically-unrolled halves with a sched_barrier between: caps the
  // load-hoisting spike (16 in-flight w2 f32x4 = 64 VGPRs); this is what
  // brought natural VGPR usage to 56 in r15.
  {
    v2f ssv = {0.f, 0.f};
    #pragma unroll
    for (int i = 0; i < 8; ++i) ssv = fma2(v1[i], v1[i], ssv);
    float ss = ssv.x + ssv.y;
    ss += fshfl_xor(ss, 32);
    float lam = fsqrt(ss);
    float sc1 = (lam > 0.f) ? (fsqrt(fmaxf(lam, 1e-4f)) * frcp(lam)) : 0.f;
    f32x4 acc0 = {0.f,0.f,0.f,0.f}, acc1 = acc0, acc2 = acc0, acc3 = acc0;
    #pragma unroll
    for (int t = 0; t < 4; ++t) {
      int rr = (h << 4) + 2 * t;
      const f32x4* wr0 = (const f32x4*)(w2g + rr * 16);
      const f32x4* wr1 = (const f32x4*)(w2g + (rr + 1) * 16);
      float vx = v1[t].x, vy = v1[t].y;
      f32x4 vx4 = {vx, vx, vx, vx};
      f32x4 vy4 = {vy, vy, vy, vy};
      acc0 = fma4(wr0[0], vx4, acc0); acc1 = fma4(wr0[1], vx4, acc1);
      acc2 = fma4(wr0[2], vx4, acc2); acc3 = fma4(wr0[3], vx4, acc3);
      acc0 = fma4(wr1[0], vy4, acc0); acc1 = fma4(wr1[1], vy4, acc1);
      acc2 = fma4(wr1[2], vy4, acc2); acc3 = fma4(wr1[3], vy4, acc3);
    }
    __builtin_amdgcn_sched_barrier(0);   // don't hoist 2nd-half loads above
    #pragma unroll
    for (int t = 4; t < 8; ++t) {
      int rr = (h << 4) + 2 * t;
      const f32x4* wr0 = (const f32x4*)(w2g + rr * 16);
      const f32x4* wr1 = (const f32x4*)(w2g + (rr + 1) * 16);
      float vx = v1[t].x, vy = v1[t].y;
      f32x4 vx4 = {vx, vx, vx, vx};
      f32x4 vy4 = {vy, vy, vy, vy};
      acc0 = fma4(wr0[0], vx4, acc0); acc1 = fma4(wr0[1], vx4, acc1);
      acc2 = fma4(wr0[2], vx4, acc2); acc3 = fma4(wr0[3], vx4, acc3);
      acc0 = fma4(wr1[0], vy4, acc0); acc1 = fma4(wr1[1], vy4, acc1);
      acc2 = fma4(wr1[2], vy4, acc2); acc3 = fma4(wr1[3], vy4, acc3);
    }
    acc0.x = (acc0.x + fshfl_xor(acc0.x, 32)) * sc1;
    acc0.y = (acc0.y + fshfl_xor(acc0.y, 32)) * sc1;
    acc0.z = (acc0.z + fshfl_xor(acc0.z, 32)) * sc1;
    acc0.w = (acc0.w + fshfl_xor(acc0.w, 32)) * sc1;
    acc1.x = (acc1.x + fshfl_xor(acc1.x, 32)) * sc1;
    acc1.y = (acc1.y + fshfl_xor(acc1.y, 32)) * sc1;
    acc1.z = (acc1.z + fshfl_xor(acc1.z, 32)) * sc1;
    acc1.w = (acc1.w + fshfl_xor(acc1.w, 32)) * sc1;
    acc2.x = (acc2.x + fshfl_xor(acc2.x, 32)) * sc1;
    acc2.y = (acc2.y + fshfl_xor(acc2.y, 32)) * sc1;
    acc2.z = (acc2.z + fshfl_xor(acc2.z, 32)) * sc1;
    acc2.w = (acc2.w + fshfl_xor(acc2.w, 32)) * sc1;
    acc3.x = (acc3.x + fshfl_xor(acc3.x, 32)) * sc1;
    acc3.y = (acc3.y + fshfl_xor(acc3.y, 32)) * sc1;
    acc3.z = (acc3.z + fshfl_xor(acc3.z, 32)) * sc1;
    acc3.w = (acc3.w + fshfl_xor(acc3.w, 32)) * sc1;
    // lane (j,h) stores Ps[j][8h..8h+7]: h=0 -> acc0/acc1, h=1 -> acc2/acc3
    f32x4 lo = h ? acc2 : acc0;
    f32x4 hi = h ? acc3 : acc1;
    const int jb8 = h << 3;
    Pt[(jb8 + 0) * PT_S + j] = lo.x;
    Pt[(jb8 + 1) * PT_S + j] = lo.y;
    Pt[(jb8 + 2) * PT_S + j] = lo.z;
    Pt[(jb8 + 3) * PT_S + j] = lo.w;
    Pt[(jb8 + 4) * PT_S + j] = hi.x;
    Pt[(jb8 + 5) * PT_S + j] = hi.y;
    Pt[(jb8 + 6) * PT_S + j] = hi.z;
    Pt[(jb8 + 7) * PT_S + j] = hi.w;
  }
  FENCE();

  // ---------------- M2 = Ps^T Ps directly into stage-2 registers.
  // lane = c2 + 16*h4 owns rows 4h4..4h4+3 of M2 column c2.
  // (kk-loop unroll 2 safe: only LDS pointers use kk.)
  const int c2 = lane & 15;
  const int h4 = lane >> 4;
  f32x4 v2r;
  {
    v2f a0 = {0.f,0.f}, a1 = {0.f,0.f}, a2 = {0.f,0.f}, a3 = {0.f,0.f};
    #pragma unroll 2
    for (int kk = 0; kk < 32; kk += 4) {
      f32x4 aa = *(const f32x4*)(Pt + c2 * PT_S + kk);
      f32x4 b0 = *(const f32x4*)(Pt + (4 * h4 + 0) * PT_S + kk);
      f32x4 b1 = *(const f32x4*)(Pt + (4 * h4 + 1) * PT_S + kk);
      f32x4 b2 = *(const f32x4*)(Pt + (4 * h4 + 2) * PT_S + kk);
      f32x4 b3 = *(const f32x4*)(Pt + (4 * h4 + 3) * PT_S + kk);
      a0 = fma2(aa.lo, b0.lo, a0); a0 = fma2(aa.hi, b0.hi, a0);
      a1 = fma2(aa.lo, b1.lo, a1); a1 = fma2(aa.hi, b1.hi, a1);
      a2 = fma2(aa.lo, b2.lo, a2); a2 = fma2(aa.hi, b2.hi, a2);
      a3 = fma2(aa.lo, b3.lo, a3); a3 = fma2(aa.hi, b3.hi, a3);
    }
    v2r.x = a0.x + a0.y;
    v2r.y = a1.x + a1.y;
    v2r.z = a2.x + a2.y;
    v2r.w = a3.x + a3.y;
  }

  // ---------------- one-sided Jacobi, n=16, register-resident, XOR
  // tournament, incremental norms.
  {
    #pragma unroll 1
    for (int sweep = 0; sweep < 6; ++sweep) {
      v2f sp = fma2(v2r.hi, v2r.hi, v2r.lo * v2r.lo);
      float sn2 = sp.x + sp.y;
      sn2 += fshfl_xor(sn2, 16);
      sn2 += fshfl_xor(sn2, 32);
      float offmax = 0.f;
      #pragma unroll 1
      for (int mask = 1; mask < 16; ++mask) {
        const int m = c2 ^ mask;
        float u0 = fshfl_xor(v2r.x, mask);
        float u1 = fshfl_xor(v2r.y, mask);
        float u2 = fshfl_xor(v2r.z, mask);
        float u3 = fshfl_xor(v2r.w, mask);
        float sb_o = fshfl_xor(sn2, mask);
        v2f ua = {u0, u1}, ub = {u2, u3};
        v2f sgv = fma2(v2r.hi, ub, v2r.lo * ua);
        float sg = sgv.x + sgv.y;
        sg += fshfl_xor(sg, 16);
        sg += fshfl_xor(sg, 32);
        const bool isp = c2 < m;
        float nA = isp ? sn2 : sb_o;
        float nB = isp ? sb_o : sn2;
        float rel = sg * sg * frcp(fmaxf(nA * nB, 1e-30f));
        offmax = fmaxf(offmax, rel);
        if (rel > 1e-13f) {
          float uc = 0.5f * (nB - nA);
          float R  = fsqrt(uc * uc + sg * sg);
          float t  = sg * frcp(uc + ((uc >= 0.f) ? R : -R));
          float ct = frsq(1.f + t * t);
          float st = ct * t;
          float s  = isp ? -st : st;
          f32x4 ct4 = {ct, ct, ct, ct};
          f32x4 s4  = {s, s, s, s};
          f32x4 uu4 = {u0, u1, u2, u3};
          v2r = fma4(uu4, s4, v2r * ct4);
          sn2 = fmaxf(isp ? (nA - t * sg) : (nB + t * sg), 0.f);
        }
      }
      #pragma unroll
      for (int mm = 1; mm <= 32; mm <<= 1) offmax = fmaxf(offmax, fshfl_xor(offmax, mm));
      if (offmax < 1e-11f) break;
    }
  }

  // ---------------- Qb row c2 = (V2^T w3)[c2][:] * sqrt(clamp(lam2)) from regs
  {
    f32x4 qq = {0.f, 0.f, 0.f, 0.f};
    f32x4 w0 = *(const f32x4*)(w3g + (4 * h4 + 0) * 4);
    f32x4 w1r = *(const f32x4*)(w3g + (4 * h4 + 1) * 4);
    f32x4 w2r = *(const f32x4*)(w3g + (4 * h4 + 2) * 4);
    f32x4 w3r = *(const f32x4*)(w3g + (4 * h4 + 3) * 4);
    f32x4 vv0 = {v2r.x, v2r.x, v2r.x, v2r.x};
    f32x4 vv1 = {v2r.y, v2r.y, v2r.y, v2r.y};
    f32x4 vv2 = {v2r.z, v2r.z, v2r.z, v2r.z};
    f32x4 vv3 = {v2r.w, v2r.w, v2r.w, v2r.w};
    qq = fma4(w0, vv0, qq); qq = fma4(w1r, vv1, qq);
    qq = fma4(w2r, vv2, qq); qq = fma4(w3r, vv3, qq);
    v2f sp = fma2(v2r.hi, v2r.hi, v2r.lo * v2r.lo);
    float ssp = sp.x + sp.y;
    float q0 = qq.x, q1 = qq.y, q2 = qq.z, q3 = qq.w;
    q0 += fshfl_xor(q0, 16); q0 += fshfl_xor(q0, 32);
    q1 += fshfl_xor(q1, 16); q1 += fshfl_xor(q1, 32);
    q2 += fshfl_xor(q2, 16); q2 += fshfl_xor(q2, 32);
    q3 += fshfl_xor(q3, 16); q3 += fshfl_xor(q3, 32);
    ssp += fshfl_xor(ssp, 16); ssp += fshfl_xor(ssp, 32);
    float lam = fsqrt(ssp);
    float scl = (lam > 0.f) ? (frcp(lam) * fsqrt(fmaxf(lam, 1e-4f))) : 0.f;
    if (h4 == 0)
      *(f32x4*)(Cc + c2 * 4) = (f32x4){q0 * scl, q1 * scl, q2 * scl, q3 * scl};
  }
  FENCE();

  // ---------------- stage 3: one-sided Jacobi ON THE 16x4 FACTOR, with
  // accumulated rotations J (eigenvectors of M3 = Q^T Q). 5 sweeps.
  float qv = Cc[lane];            // Qb[kq][jq], kq*4+jq == lane
  const int kq = lane >> 2;
  const int jq = lane & 3;
  float jv = (kq == jq) ? 1.f : 0.f;
  {
    #define ROT3(P_, Q_) do {                                             \
      float w_ = fshfl_xor(qv, (P_) ^ (Q_));                              \
      float s1 = qv * qv, s2 = w_ * w_, s3 = qv * w_;                     \
      s1 += fshfl_xor(s1, 4);  s2 += fshfl_xor(s2, 4);  s3 += fshfl_xor(s3, 4);  \
      s1 += fshfl_xor(s1, 8);  s2 += fshfl_xor(s2, 8);  s3 += fshfl_xor(s3, 8);  \
      s1 += fshfl_xor(s1, 16); s2 += fshfl_xor(s2, 16); s3 += fshfl_xor(s3, 16); \
      s1 += fshfl_xor(s1, 32); s2 += fshfl_xor(s2, 32); s3 += fshfl_xor(s3, 32); \
      bool isp = (jq == (P_)), isq = (jq == (Q_));                        \
      float sa = isp ? s1 : s2;                                           \
      float sb = isp ? s2 : s1;                                           \
      float u_ = 0.5f * (sb - sa);                                        \
      float R_ = fsqrt(u_ * u_ + s3 * s3);                                \
      float dn_ = u_ + copysignf(fmaxf(R_, 1e-30f), u_);                  \
      float t_ = s3 * frcp(dn_);                                          \
      float ct = frsq(1.f + t_ * t_);                                     \
      float st = ct * t_;                                                 \
      float wj_ = fshfl_xor(jv, (P_) ^ (Q_));                             \
      float nv  = isp ? (ct * qv - st * w_)  : (st * w_  + ct * qv);      \
      float nvj = isp ? (ct * jv - st * wj_) : (st * wj_ + ct * jv);      \
      if (isp | isq) { qv = nv; jv = nvj; }                               \
    } while (0)

    #pragma unroll 1
    for (int sweep = 0; sweep < 5; ++sweep) {
      ROT3(0,1); ROT3(2,3); ROT3(0,2); ROT3(1,3); ROT3(0,3); ROT3(1,2);
    }
    #undef ROT3
  }

  // ---------------- lambda_3 = ||col||^2, LogEig via J, FC, log_softmax
  {
    float ss = qv * qv;
    ss += fshfl_xor(ss, 4); ss += fshfl_xor(ss, 8);
    ss += fshfl_xor(ss, 16); ss += fshfl_xor(ss, 32);
    float lwv = logf(fmaxf(ss, 1e-10f));       // log eigenvalue of column jq
    if (kq < 4)  Cc[64 + kq * 4 + jq] = jv;    // J, row-major 4x4
    if (kq == 0) Cc[80 + jq] = lwv;            // lanes 0..3: per-column loglam
    FENCE();

    float f = 0.f;
    if (lane < 16) {
      int i3 = lane >> 2, j3 = lane & 3;
      #pragma unroll
      for (int c = 0; c < 4; ++c)
        f += Cc[80 + c] * Cc[64 + i3 * 4 + c] * Cc[64 + j3 * 4 + c];
    }
    float t0 = 0.f, t1 = 0.f;
    if (lane < 16) { t0 = f * fcg[2 * lane]; t1 = f * fcg[2 * lane + 1]; }
    t0 += fshfl_xor(t0, 1); t1 += fshfl_xor(t1, 1);
    t0 += fshfl_xor(t0, 2); t1 += fshfl_xor(t1, 2);
    t0 += fshfl_xor(t0, 4); t1 += fshfl_xor(t1, 4);
    t0 += fshfl_xor(t0, 8); t1 += fshfl_xor(t1, 8);
    float mx  = fmaxf(t0, t1);
    float lse = mx + logf(expf(t0 - mx) + expf(t1 - mx));

    float* outFeat = outg + (size_t)B * 2;
    if (lane < 16) outFeat[(size_t)b * 16 + lane] = f;
    if (lane < 2)  outg[(size_t)b * 2 + lane] = (lane == 0 ? t0 : t1) - lse;
  }
}

extern "C" void kernel_launch(void* const* d_in, const int* in_sizes, int n_in,
                              void* d_out, int out_size, void* d_ws, size_t ws_size,
                              hipStream_t stream) {
  const float* x  = (const float*)d_in[0];
  const float* w1 = (const float*)d_in[1];
  const float* w2 = (const float*)d_in[2];
  const float* w3 = (const float*)d_in[3];
  const float* fc = (const float*)d_in[4];
  float* out = (float*)d_out;
  int B = in_sizes[0] / 1024;
  int grid = (B + 3) / 4;
  hipLaunchKernelGGL(spd_fused, dim3(grid), dim3(256), 0, stream,
                     x, w1, w2, w3, fc, out, B);
}

// Round 18
// 1641.083 us; speedup vs baseline: 1.2625x; 1.2596x over previous
//
#include <hip/hip_runtime.h>

// Wave-level LDS ordering fence for the few remaining LDS phase transitions.
#define FENCE() asm volatile("s_waitcnt lgkmcnt(0)" ::: "memory")

typedef float v2f   __attribute__((ext_vector_type(2)));
typedef float f32x4 __attribute__((ext_vector_type(4)));

__device__ __forceinline__ float fshfl_xor(float v, int m) { return __shfl_xor(v, m, 64); }
__device__ __forceinline__ float fsqrt(float x) { return __builtin_amdgcn_sqrtf(x); }
__device__ __forceinline__ float frcp (float x) { return __builtin_amdgcn_rcpf(x); }
__device__ __forceinline__ float frsq (float x) { return __builtin_amdgcn_rsqf(x); }
__device__ __forceinline__ v2f   fma2(v2f a, v2f b, v2f c)       { return __builtin_elementwise_fma(a, b, c); }
__device__ __forceinline__ f32x4 fma4(f32x4 a, f32x4 b, f32x4 c) { return __builtin_elementwise_fma(a, b, c); }

// ---- VALU-pipe lane exchange (r18): the kernel is DS-pipe-bound (dur
// invariant at 2030-2080us across occupancy 46..87% and even 300MB spill;
// VALUBusy capped ~58% -- the per-CU LDS/DS pipe servicing all __shfl_xor
// from 4 SIMDs is the shared saturated resource, ~8cyc/DS-op measured).
// Move butterflies onto VALU: permlane16/32_swap for xor16/32 sums & maxes,
// DPP (quad_perm / mirrors) for xor 1,2,3,7,15 exchanges.
template<int C>
__device__ __forceinline__ float dppf(float x) {
  return __builtin_bit_cast(float,
      __builtin_amdgcn_mov_dpp(__builtin_bit_cast(int, x), C, 0xF, 0xF, true));
}
#define DPP_X1  0xB1   // quad_perm [1,0,3,2]
#define DPP_X2  0x4E   // quad_perm [2,3,0,1]
#define DPP_X3  0x1B   // quad_perm [3,2,1,0]
#define DPP_X7  0x141  // row_half_mirror
#define DPP_X15 0x140  // row_mirror

__device__ __forceinline__ float pl32_sum(float x) {
#if __has_builtin(__builtin_amdgcn_permlane32_swap)
  unsigned xi = __builtin_bit_cast(unsigned, x);
  auto r = __builtin_amdgcn_permlane32_swap(xi, xi, false, false);
  return __builtin_bit_cast(float, (unsigned)r[0]) +
         __builtin_bit_cast(float, (unsigned)r[1]);
#else
  return x + fshfl_xor(x, 32);
#endif
}
__device__ __forceinline__ float pl32_max(float x) {
#if __has_builtin(__builtin_amdgcn_permlane32_swap)
  unsigned xi = __builtin_bit_cast(unsigned, x);
  auto r = __builtin_amdgcn_permlane32_swap(xi, xi, false, false);
  return fmaxf(__builtin_bit_cast(float, (unsigned)r[0]),
               __builtin_bit_cast(float, (unsigned)r[1]));
#else
  return fmaxf(x, fshfl_xor(x, 32));
#endif
}
__device__ __forceinline__ float pl16_sum(float x) {
#if __has_builtin(__builtin_amdgcn_permlane16_swap)
  unsigned xi = __builtin_bit_cast(unsigned, x);
  auto r = __builtin_amdgcn_permlane16_swap(xi, xi, false, false);
  return __builtin_bit_cast(float, (unsigned)r[0]) +
         __builtin_bit_cast(float, (unsigned)r[1]);
#else
  return x + fshfl_xor(x, 16);
#endif
}
__device__ __forceinline__ float pl16_max(float x) {
#if __has_builtin(__builtin_amdgcn_permlane16_swap)
  unsigned xi = __builtin_bit_cast(unsigned, x);
  auto r = __builtin_amdgcn_permlane16_swap(xi, xi, false, false);
  return fmaxf(__builtin_bit_cast(float, (unsigned)r[0]),
               __builtin_bit_cast(float, (unsigned)r[1]));
#else
  return fmaxf(x, fshfl_xor(x, 16));
#endif
}
__device__ __forceinline__ float pl16_get(float x, int lane_) {
#if __has_builtin(__builtin_amdgcn_permlane16_swap)
  unsigned xi = __builtin_bit_cast(unsigned, x);
  auto r = __builtin_amdgcn_permlane16_swap(xi, xi, false, false);
  float a = __builtin_bit_cast(float, (unsigned)r[0]);
  float b = __builtin_bit_cast(float, (unsigned)r[1]);
  return (lane_ & 16) ? a : b;   // out0 holds x[i&~16], out1 holds x[i|16]
#else
  return fshfl_xor(x, 16);
#endif
}

// One block = 256 threads = 4 waves, one 32x32 SPD matrix per wave.
// r18 = r15 (clean build, no launch_bounds, 46% occ) with the shuffle
// traffic moved DS->VALU per the analysis above. Tournament reordered so
// DPP-able masks {1,2,3,7,15,16} are peeled (any cyclic order converges).
// Spill tripwire: WRITE_SIZE ~2.3MB. LDS: 4*1152*4 = 18432 B/block.
#define PT_S 34
__global__ __launch_bounds__(256) void spd_fused(
    const float* __restrict__ xg,
    const float* __restrict__ w1g,
    const float* __restrict__ w2g,
    const float* __restrict__ w3g,
    const float* __restrict__ fcg,
    float* __restrict__ outg,
    int B)
{
  __shared__ float slot[4][1152];

  const int tid  = threadIdx.x;
  const int wid  = tid >> 6;
  const int lane = tid & 63;

  float* Cc = slot[wid];          // x (stride 32) -> M1 cols (stride 36) -> Qb/J scratch
  float* Pt = slot[wid] + 576;    // Ps transposed [16][PT_S], in dead M1 space

  const long b = (long)blockIdx.x * 4 + wid;
  if (b >= B) return;

  // ---------------- load x -> Cc row-major [32][32] (stride 32)
  {
    const f32x4* xv = (const f32x4*)(xg + (size_t)b * 1024);
    f32x4* c4 = (f32x4*)Cc;
    #pragma unroll
    for (int jj = 0; jj < 4; ++jj) {
      int i4 = lane + 64 * jj;
      c4[i4] = xv[i4];
    }
  }
  FENCE();

  const int j = lane & 31;
  const int h = lane >> 5;

  // ---------------- Tmat = x * w1 in registers (packed). T2[e] = rows
  // {16h+2e, +1} of column j. Uses x symmetry: read x rows as f32x4.
  v2f T2[8];
  {
    #pragma unroll
    for (int e = 0; e < 8; ++e) T2[e] = (v2f){0.f, 0.f};
    const f32x4* c4 = (const f32x4*)Cc;
    #pragma unroll 4
    for (int c = 0; c < 32; ++c) {
      float wv = w1g[c * 32 + j];
      v2f wv2 = {wv, wv};
      f32x4 x0 = c4[c * 8 + h * 4 + 0];
      f32x4 x1 = c4[c * 8 + h * 4 + 1];
      f32x4 x2 = c4[c * 8 + h * 4 + 2];
      f32x4 x3 = c4[c * 8 + h * 4 + 3];
      T2[0] = fma2(x0.lo, wv2, T2[0]); T2[1] = fma2(x0.hi, wv2, T2[1]);
      T2[2] = fma2(x1.lo, wv2, T2[2]); T2[3] = fma2(x1.hi, wv2, T2[3]);
      T2[4] = fma2(x2.lo, wv2, T2[4]); T2[5] = fma2(x2.hi, wv2, T2[5]);
      T2[6] = fma2(x3.lo, wv2, T2[6]); T2[7] = fma2(x3.hi, wv2, T2[7]);
    }
  }
  FENCE();   // all x reads complete before M1 overwrites Cc

  // ---------------- M1 = w1^T * Tmat -> Cc linear column-major, stride 36.
  {
    const f32x4* w14 = (const f32x4*)w1g;   // row r = w14[r*8 + 0..7]
    #pragma unroll
    for (int ih2 = 0; ih2 < 4; ++ih2) {     // output rows 8*ih2 .. 8*ih2+7
      f32x4 A = {0.f, 0.f, 0.f, 0.f};
      f32x4 Bv = {0.f, 0.f, 0.f, 0.f};
      #pragma unroll
      for (int e = 0; e < 16; ++e) {
        int r = 16 * h + e;
        float tv = T2[e >> 1][e & 1];
        f32x4 tv4 = {tv, tv, tv, tv};
        A  = fma4(w14[r * 8 + ih2 * 2],     tv4, A);
        Bv = fma4(w14[r * 8 + ih2 * 2 + 1], tv4, Bv);
      }
      A.x = pl32_sum(A.x);  A.y = pl32_sum(A.y);
      A.z = pl32_sum(A.z);  A.w = pl32_sum(A.w);
      Bv.x = pl32_sum(Bv.x); Bv.y = pl32_sum(Bv.y);
      Bv.z = pl32_sum(Bv.z); Bv.w = pl32_sum(Bv.w);
      if (h == (ih2 & 1)) {
        *(f32x4*)(Cc + j * 36 + ih2 * 8)     = A;
        *(f32x4*)(Cc + j * 36 + ih2 * 8 + 4) = Bv;
      }
    }
  }
  FENCE();

  // ---------------- load own column half into v2f registers (one-time)
  v2f v1[8];
  {
    const float* bp = Cc + j * 36 + (h << 4);
    f32x4 q0 = *(const f32x4*)(bp);
    f32x4 q1 = *(const f32x4*)(bp + 4);
    f32x4 q2 = *(const f32x4*)(bp + 8);
    f32x4 q3 = *(const f32x4*)(bp + 12);
    v1[0] = q0.lo; v1[1] = q0.hi; v1[2] = q1.lo; v1[3] = q1.hi;
    v1[4] = q2.lo; v1[5] = q2.hi; v1[6] = q3.lo; v1[7] = q3.hi;
  }

  // ---------------- one-sided Jacobi, n=32, register-resident, XOR
  // tournament (peeled DPP rounds first), incremental norms.
  {
    #define S1ROUND(MVAL, GETF) do {                                       \
      const int m_ = j ^ (MVAL);                                           \
      v2f uu[8];                                                           \
      _Pragma("unroll") for (int i = 0; i < 8; ++i) {                      \
        uu[i].x = GETF(v1[i].x); uu[i].y = GETF(v1[i].y); }                \
      float sb_o = GETF(sn);                                               \
      v2f sgv = {0.f, 0.f};                                                \
      _Pragma("unroll") for (int i = 0; i < 8; ++i)                        \
        sgv = fma2(v1[i], uu[i], sgv);                                     \
      float sg = pl32_sum(sgv.x + sgv.y);                                  \
      const bool isp = j < m_;                                             \
      float nA = isp ? sn : sb_o;                                          \
      float nB = isp ? sb_o : sn;                                          \
      float rel = sg * sg * frcp(fmaxf(nA * nB, 1e-30f));                  \
      offmax = fmaxf(offmax, rel);                                         \
      if (rel > 1e-13f) {                                                  \
        float uc = 0.5f * (nB - nA);                                       \
        float R  = fsqrt(uc * uc + sg * sg);                               \
        float t  = sg * frcp(uc + ((uc >= 0.f) ? R : -R));                 \
        float ct = frsq(1.f + t * t);                                      \
        float st = ct * t;                                                 \
        float s_ = isp ? -st : st;                                         \
        v2f ct2 = {ct, ct}, sv2 = {s_, s_};                                \
        _Pragma("unroll") for (int i = 0; i < 8; ++i)                      \
          v1[i] = fma2(uu[i], sv2, v1[i] * ct2);                           \
        sn = fmaxf(isp ? (nA - t * sg) : (nB + t * sg), 0.f);              \
      }                                                                    \
    } while (0)
    #define G_D1(v)  dppf<DPP_X1>(v)
    #define G_D2(v)  dppf<DPP_X2>(v)
    #define G_D3(v)  dppf<DPP_X3>(v)
    #define G_D7(v)  dppf<DPP_X7>(v)
    #define G_D15(v) dppf<DPP_X15>(v)
    #define G_P16(v) pl16_get(v, lane)
    #define G_RT(v)  fshfl_xor(v, mask)

    #pragma unroll 1
    for (int sweep = 0; sweep < 8; ++sweep) {
      // fresh own-norm (kills incremental drift)
      v2f s2n = {0.f, 0.f};
      #pragma unroll
      for (int i = 0; i < 8; ++i) s2n = fma2(v1[i], v1[i], s2n);
      float sn = pl32_sum(s2n.x + s2n.y);

      float offmax = 0.f;
      // peeled VALU-pipe rounds (DPP / permlane)
      S1ROUND(1,  G_D1);
      S1ROUND(2,  G_D2);
      S1ROUND(3,  G_D3);
      S1ROUND(7,  G_D7);
      S1ROUND(15, G_D15);
      S1ROUND(16, G_P16);
      // remaining masks on the DS pipe
      #pragma unroll 1
      for (int mask = 4; mask < 7; ++mask)   S1ROUND(mask, G_RT);
      #pragma unroll 1
      for (int mask = 8; mask < 15; ++mask)  S1ROUND(mask, G_RT);
      #pragma unroll 1
      for (int mask = 17; mask < 32; ++mask) S1ROUND(mask, G_RT);

      offmax = fmaxf(offmax, dppf<DPP_X1>(offmax));
      offmax = fmaxf(offmax, dppf<DPP_X2>(offmax));
      offmax = fmaxf(offmax, fshfl_xor(offmax, 4));
      offmax = fmaxf(offmax, fshfl_xor(offmax, 8));
      offmax = pl16_max(offmax);
      offmax = pl32_max(offmax);
      if (offmax < 1e-11f) break;
    }
  }

  // ---------------- lambda_1 + ReEig + Ps = sqrt(clamp(lam1))*v1hat^T w2,
  // all from registers; Pt[16][PT_S] transposed (conflict-free).
  // Split halves with sched_barrier: caps the w2-load hoisting spike.
  {
    v2f ssv = {0.f, 0.f};
    #pragma unroll
    for (int i = 0; i < 8; ++i) ssv = fma2(v1[i], v1[i], ssv);
    float ss = pl32_sum(ssv.x + ssv.y);
    float lam = fsqrt(ss);
    float sc1 = (lam > 0.f) ? (fsqrt(fmaxf(lam, 1e-4f)) * frcp(lam)) : 0.f;
    f32x4 acc0 = {0.f,0.f,0.f,0.f}, acc1 = acc0, acc2 = acc0, acc3 = acc0;
    #pragma unroll
    for (int t = 0; t < 4; ++t) {
      int rr = (h << 4) + 2 * t;
      const f32x4* wr0 = (const f32x4*)(w2g + rr * 16);
      const f32x4* wr1 = (const f32x4*)(w2g + (rr + 1) * 16);
      float vx = v1[t].x, vy = v1[t].y;
      f32x4 vx4 = {vx, vx, vx, vx};
      f32x4 vy4 = {vy, vy, vy, vy};
      acc0 = fma4(wr0[0], vx4, acc0); acc1 = fma4(wr0[1], vx4, acc1);
      acc2 = fma4(wr0[2], vx4, acc2); acc3 = fma4(wr0[3], vx4, acc3);
      acc0 = fma4(wr1[0], vy4, acc0); acc1 = fma4(wr1[1], vy4, acc1);
      acc2 = fma4(wr1[2], vy4, acc2); acc3 = fma4(wr1[3], vy4, acc3);
    }
    __builtin_amdgcn_sched_barrier(0);   // don't hoist 2nd-half loads above
    #pragma unroll
    for (int t = 4; t < 8; ++t) {
      int rr = (h << 4) + 2 * t;
      const f32x4* wr0 = (const f32x4*)(w2g + rr * 16);
      const f32x4* wr1 = (const f32x4*)(w2g + (rr + 1) * 16);
      float vx = v1[t].x, vy = v1[t].y;
      f32x4 vx4 = {vx, vx, vx, vx};
      f32x4 vy4 = {vy, vy, vy, vy};
      acc0 = fma4(wr0[0], vx4, acc0); acc1 = fma4(wr0[1], vx4, acc1);
      acc2 = fma4(wr0[2], vx4, acc2); acc3 = fma4(wr0[3], vx4, acc3);
      acc0 = fma4(wr1[0], vy4, acc0); acc1 = fma4(wr1[1], vy4, acc1);
      acc2 = fma4(wr1[2], vy4, acc2); acc3 = fma4(wr1[3], vy4, acc3);
    }
    acc0.x = pl32_sum(acc0.x) * sc1;  acc0.y = pl32_sum(acc0.y) * sc1;
    acc0.z = pl32_sum(acc0.z) * sc1;  acc0.w = pl32_sum(acc0.w) * sc1;
    acc1.x = pl32_sum(acc1.x) * sc1;  acc1.y = pl32_sum(acc1.y) * sc1;
    acc1.z = pl32_sum(acc1.z) * sc1;  acc1.w = pl32_sum(acc1.w) * sc1;
    acc2.x = pl32_sum(acc2.x) * sc1;  acc2.y = pl32_sum(acc2.y) * sc1;
    acc2.z = pl32_sum(acc2.z) * sc1;  acc2.w = pl32_sum(acc2.w) * sc1;
    acc3.x = pl32_sum(acc3.x) * sc1;  acc3.y = pl32_sum(acc3.y) * sc1;
    acc3.z = pl32_sum(acc3.z) * sc1;  acc3.w = pl32_sum(acc3.w) * sc1;
    // lane (j,h) stores Ps[j][8h..8h+7]: h=0 -> acc0/acc1, h=1 -> acc2/acc3
    f32x4 lo = h ? acc2 : acc0;
    f32x4 hi = h ? acc3 : acc1;
    const int jb8 = h << 3;
    Pt[(jb8 + 0) * PT_S + j] = lo.x;
    Pt[(jb8 + 1) * PT_S + j] = lo.y;
    Pt[(jb8 + 2) * PT_S + j] = lo.z;
    Pt[(jb8 + 3) * PT_S + j] = lo.w;
    Pt[(jb8 + 4) * PT_S + j] = hi.x;
    Pt[(jb8 + 5) * PT_S + j] = hi.y;
    Pt[(jb8 + 6) * PT_S + j] = hi.z;
    Pt[(jb8 + 7) * PT_S + j] = hi.w;
  }
  FENCE();

  // ---------------- M2 = Ps^T Ps directly into stage-2 registers.
  // lane = c2 + 16*h4 owns rows 4h4..4h4+3 of M2 column c2.
  const int c2 = lane & 15;
  const int h4 = lane >> 4;
  f32x4 v2r;
  {
    v2f a0 = {0.f,0.f}, a1 = {0.f,0.f}, a2 = {0.f,0.f}, a3 = {0.f,0.f};
    #pragma unroll 2
    for (int kk = 0; kk < 32; kk += 4) {
      f32x4 aa = *(const f32x4*)(Pt + c2 * PT_S + kk);
      f32x4 b0 = *(const f32x4*)(Pt + (4 * h4 + 0) * PT_S + kk);
      f32x4 b1 = *(const f32x4*)(Pt + (4 * h4 + 1) * PT_S + kk);
      f32x4 b2 = *(const f32x4*)(Pt + (4 * h4 + 2) * PT_S + kk);
      f32x4 b3 = *(const f32x4*)(Pt + (4 * h4 + 3) * PT_S + kk);
      a0 = fma2(aa.lo, b0.lo, a0); a0 = fma2(aa.hi, b0.hi, a0);
      a1 = fma2(aa.lo, b1.lo, a1); a1 = fma2(aa.hi, b1.hi, a1);
      a2 = fma2(aa.lo, b2.lo, a2); a2 = fma2(aa.hi, b2.hi, a2);
      a3 = fma2(aa.lo, b3.lo, a3); a3 = fma2(aa.hi, b3.hi, a3);
    }
    v2r.x = a0.x + a0.y;
    v2r.y = a1.x + a1.y;
    v2r.z = a2.x + a2.y;
    v2r.w = a3.x + a3.y;
  }

  // ---------------- one-sided Jacobi, n=16, register-resident, XOR
  // tournament (peeled DPP rounds), incremental norms.
  {
    #define S2ROUND(MVAL, GETF) do {                                       \
      const int m_ = c2 ^ (MVAL);                                          \
      float u0 = GETF(v2r.x), u1 = GETF(v2r.y);                            \
      float u2 = GETF(v2r.z), u3 = GETF(v2r.w);                            \
      float sb_o = GETF(sn2);                                              \
      v2f ua = {u0, u1}, ub = {u2, u3};                                    \
      v2f sgv = fma2(v2r.hi, ub, v2r.lo * ua);                             \
      float sg = pl32_sum(pl16_sum(sgv.x + sgv.y));                        \
      const bool isp = c2 < m_;                                            \
      float nA = isp ? sn2 : sb_o;                                         \
      float nB = isp ? sb_o : sn2;                                         \
      float rel = sg * sg * frcp(fmaxf(nA * nB, 1e-30f));                  \
      offmax = fmaxf(offmax, rel);                                         \
      if (rel > 1e-13f) {                                                  \
        float uc = 0.5f * (nB - nA);                                       \
        float R  = fsqrt(uc * uc + sg * sg);                               \
        float t  = sg * frcp(uc + ((uc >= 0.f) ? R : -R));                 \
        float ct = frsq(1.f + t * t);                                      \
        float st = ct * t;                                                 \
        float s_ = isp ? -st : st;                                         \
        f32x4 ct4 = {ct, ct, ct, ct};                                      \
        f32x4 s4  = {s_, s_, s_, s_};                                      \
        f32x4 uu4 = {u0, u1, u2, u3};                                      \
        v2r = fma4(uu4, s4, v2r * ct4);                                    \
        sn2 = fmaxf(isp ? (nA - t * sg) : (nB + t * sg), 0.f);             \
      }                                                                    \
    } while (0)

    #pragma unroll 1
    for (int sweep = 0; sweep < 6; ++sweep) {
      v2f sp = fma2(v2r.hi, v2r.hi, v2r.lo * v2r.lo);
      float sn2 = pl32_sum(pl16_sum(sp.x + sp.y));
      float offmax = 0.f;
      S2ROUND(1,  G_D1);
      S2ROUND(2,  G_D2);
      S2ROUND(3,  G_D3);
      S2ROUND(7,  G_D7);
      S2ROUND(15, G_D15);
      #pragma unroll 1
      for (int mask = 4; mask < 7; ++mask)  S2ROUND(mask, G_RT);
      #pragma unroll 1
      for (int mask = 8; mask < 15; ++mask) S2ROUND(mask, G_RT);

      offmax = fmaxf(offmax, dppf<DPP_X1>(offmax));
      offmax = fmaxf(offmax, dppf<DPP_X2>(offmax));
      offmax = fmaxf(offmax, fshfl_xor(offmax, 4));
      offmax = fmaxf(offmax, fshfl_xor(offmax, 8));
      offmax = pl16_max(offmax);
      offmax = pl32_max(offmax);
      if (offmax < 1e-11f) break;
    }
  }

  // ---------------- Qb row c2 = (V2^T w3)[c2][:] * sqrt(clamp(lam2)) from regs
  {
    f32x4 qq = {0.f, 0.f, 0.f, 0.f};
    f32x4 w0 = *(const f32x4*)(w3g + (4 * h4 + 0) * 4);
    f32x4 w1r = *(const f32x4*)(w3g + (4 * h4 + 1) * 4);
    f32x4 w2r = *(const f32x4*)(w3g + (4 * h4 + 2) * 4);
    f32x4 w3r = *(const f32x4*)(w3g + (4 * h4 + 3) * 4);
    f32x4 vv0 = {v2r.x, v2r.x, v2r.x, v2r.x};
    f32x4 vv1 = {v2r.y, v2r.y, v2r.y, v2r.y};
    f32x4 vv2 = {v2r.z, v2r.z, v2r.z, v2r.z};
    f32x4 vv3 = {v2r.w, v2r.w, v2r.w, v2r.w};
    qq = fma4(w0, vv0, qq); qq = fma4(w1r, vv1, qq);
    qq = fma4(w2r, vv2, qq); qq = fma4(w3r, vv3, qq);
    v2f sp = fma2(v2r.hi, v2r.hi, v2r.lo * v2r.lo);
    float ssp = sp.x + sp.y;
    float q0 = pl32_sum(pl16_sum(qq.x));
    float q1 = pl32_sum(pl16_sum(qq.y));
    float q2 = pl32_sum(pl16_sum(qq.z));
    float q3 = pl32_sum(pl16_sum(qq.w));
    ssp = pl32_sum(pl16_sum(ssp));
    float lam = fsqrt(ssp);
    float scl = (lam > 0.f) ? (frcp(lam) * fsqrt(fmaxf(lam, 1e-4f))) : 0.f;
    if (h4 == 0)
      *(f32x4*)(Cc + c2 * 4) = (f32x4){q0 * scl, q1 * scl, q2 * scl, q3 * scl};
  }
  FENCE();

  // ---------------- stage 3: one-sided Jacobi ON THE 16x4 FACTOR, with
  // accumulated rotations J (eigenvectors of M3 = Q^T Q). 5 sweeps.
  // All ROT3 exchange masks are in {1,2,3} -> DPP; 16/32 reduces -> permlane.
  float qv = Cc[lane];            // Qb[kq][jq], kq*4+jq == lane
  const int kq = lane >> 2;
  const int jq = lane & 3;
  float jv = (kq == jq) ? 1.f : 0.f;
  {
    #define ROT3(P_, Q_, DC_) do {                                        \
      float w_ = dppf<DC_>(qv);                                           \
      float s1 = qv * qv, s2 = w_ * w_, s3 = qv * w_;                     \
      s1 += fshfl_xor(s1, 4);  s2 += fshfl_xor(s2, 4);  s3 += fshfl_xor(s3, 4); \
      s1 += fshfl_xor(s1, 8);  s2 += fshfl_xor(s2, 8);  s3 += fshfl_xor(s3, 8); \
      s1 = pl16_sum(s1); s2 = pl16_sum(s2); s3 = pl16_sum(s3);            \
      s1 = pl32_sum(s1); s2 = pl32_sum(s2); s3 = pl32_sum(s3);            \
      bool isp = (jq == (P_)), isq = (jq == (Q_));                        \
      float sa = isp ? s1 : s2;                                           \
      float sb = isp ? s2 : s1;                                           \
      float u_ = 0.5f * (sb - sa);                                        \
      float R_ = fsqrt(u_ * u_ + s3 * s3);                                \
      float dn_ = u_ + copysignf(fmaxf(R_, 1e-30f), u_);                  \
      float t_ = s3 * frcp(dn_);                                          \
      float ct = frsq(1.f + t_ * t_);                                     \
      float st = ct * t_;                                                 \
      float wj_ = dppf<DC_>(jv);                                          \
      float nv  = isp ? (ct * qv - st * w_)  : (st * w_  + ct * qv);      \
      float nvj = isp ? (ct * jv - st * wj_) : (st * wj_ + ct * jv);      \
      if (isp | isq) { qv = nv; jv = nvj; }                               \
    } while (0)

    #pragma unroll 1
    for (int sweep = 0; sweep < 5; ++sweep) {
      ROT3(0,1,DPP_X1); ROT3(2,3,DPP_X1);
      ROT3(0,2,DPP_X2); ROT3(1,3,DPP_X2);
      ROT3(0,3,DPP_X3); ROT3(1,2,DPP_X3);
    }
    #undef ROT3
  }

  // ---------------- lambda_3 = ||col||^2, LogEig via J, FC, log_softmax
  {
    float ss = qv * qv;
    ss += fshfl_xor(ss, 4); ss += fshfl_xor(ss, 8);
    ss = pl16_sum(ss); ss = pl32_sum(ss);
    float lwv = logf(fmaxf(ss, 1e-10f));       // log eigenvalue of column jq
    if (kq < 4)  Cc[64 + kq * 4 + jq] = jv;    // J, row-major 4x4
    if (kq == 0) Cc[80 + jq] = lwv;            // lanes 0..3: per-column loglam
    FENCE();

    float f = 0.f;
    if (lane < 16) {
      int i3 = lane >> 2, j3 = lane & 3;
      #pragma unroll
      for (int c = 0; c < 4; ++c)
        f += Cc[80 + c] * Cc[64 + i3 * 4 + c] * Cc[64 + j3 * 4 + c];
    }
    float t0 = 0.f, t1 = 0.f;
    if (lane < 16) { t0 = f * fcg[2 * lane]; t1 = f * fcg[2 * lane + 1]; }
    t0 += dppf<DPP_X1>(t0); t1 += dppf<DPP_X1>(t1);
    t0 += dppf<DPP_X2>(t0); t1 += dppf<DPP_X2>(t1);
    t0 += fshfl_xor(t0, 4); t1 += fshfl_xor(t1, 4);
    t0 += fshfl_xor(t0, 8); t1 += fshfl_xor(t1, 8);
    float mx  = fmaxf(t0, t1);
    float lse = mx + logf(expf(t0 - mx) + expf(t1 - mx));

    float* outFeat = outg + (size_t)B * 2;
    if (lane < 16) outFeat[(size_t)b * 16 + lane] = f;
    if (lane < 2)  outg[(size_t)b * 2 + lane] = (lane == 0 ? t0 : t1) - lse;
  }
}

extern "C" void kernel_launch(void* const* d_in, const int* in_sizes, int n_in,
                              void* d_out, int out_size, void* d_ws, size_t ws_size,
                              hipStream_t stream) {
  const float* x  = (const float*)d_in[0];
  const float* w1 = (const float*)d_in[1];
  const float* w2 = (const float*)d_in[2];
  const float* w3 = (const float*)d_in[3];
  const float* fc = (const float*)d_in[4];
  float* out = (float*)d_out;
  int B = in_sizes[0] / 1024;
  int grid = (B + 3) / 4;
  hipLaunchKernelGGL(spd_fused, dim3(grid), dim3(256), 0, stream,
                     x, w1, w2, w3, fc, out, B);
}

// Round 19
// 1633.697 us; speedup vs baseline: 1.2682x; 1.0045x over previous
//
#include <hip/hip_runtime.h>

// Wave-level LDS ordering fence for the few remaining LDS phase transitions.
#define FENCE() asm volatile("s_waitcnt lgkmcnt(0)" ::: "memory")
#define SBAR() __builtin_amdgcn_sched_barrier(0)

typedef float v2f   __attribute__((ext_vector_type(2)));
typedef float f32x4 __attribute__((ext_vector_type(4)));

__device__ __forceinline__ float fshfl_xor(float v, int m) { return __shfl_xor(v, m, 64); }
__device__ __forceinline__ float fsqrt(float x) { return __builtin_amdgcn_sqrtf(x); }
__device__ __forceinline__ float frcp (float x) { return __builtin_amdgcn_rcpf(x); }
__device__ __forceinline__ float frsq (float x) { return __builtin_amdgcn_rsqf(x); }
__device__ __forceinline__ v2f   fma2(v2f a, v2f b, v2f c)       { return __builtin_elementwise_fma(a, b, c); }
__device__ __forceinline__ f32x4 fma4(f32x4 a, f32x4 b, f32x4 c) { return __builtin_elementwise_fma(a, b, c); }

// ---- VALU-pipe lane exchange (r18, validated: dur 2030->1641, VALU 58->85%).
template<int C>
__device__ __forceinline__ float dppf(float x) {
  return __builtin_bit_cast(float,
      __builtin_amdgcn_mov_dpp(__builtin_bit_cast(int, x), C, 0xF, 0xF, true));
}
#define DPP_X1  0xB1   // quad_perm [1,0,3,2]
#define DPP_X2  0x4E   // quad_perm [2,3,0,1]
#define DPP_X3  0x1B   // quad_perm [3,2,1,0]
#define DPP_X7  0x141  // row_half_mirror
#define DPP_X15 0x140  // row_mirror

__device__ __forceinline__ float pl32_sum(float x) {
#if __has_builtin(__builtin_amdgcn_permlane32_swap)
  unsigned xi = __builtin_bit_cast(unsigned, x);
  auto r = __builtin_amdgcn_permlane32_swap(xi, xi, false, false);
  return __builtin_bit_cast(float, (unsigned)r[0]) +
         __builtin_bit_cast(float, (unsigned)r[1]);
#else
  return x + fshfl_xor(x, 32);
#endif
}
__device__ __forceinline__ float pl32_max(float x) {
#if __has_builtin(__builtin_amdgcn_permlane32_swap)
  unsigned xi = __builtin_bit_cast(unsigned, x);
  auto r = __builtin_amdgcn_permlane32_swap(xi, xi, false, false);
  return fmaxf(__builtin_bit_cast(float, (unsigned)r[0]),
               __builtin_bit_cast(float, (unsigned)r[1]));
#else
  return fmaxf(x, fshfl_xor(x, 32));
#endif
}
__device__ __forceinline__ float pl16_sum(float x) {
#if __has_builtin(__builtin_amdgcn_permlane16_swap)
  unsigned xi = __builtin_bit_cast(unsigned, x);
  auto r = __builtin_amdgcn_permlane16_swap(xi, xi, false, false);
  return __builtin_bit_cast(float, (unsigned)r[0]) +
         __builtin_bit_cast(float, (unsigned)r[1]);
#else
  return x + fshfl_xor(x, 16);
#endif
}
__device__ __forceinline__ float pl16_max(float x) {
#if __has_builtin(__builtin_amdgcn_permlane16_swap)
  unsigned xi = __builtin_bit_cast(unsigned, x);
  auto r = __builtin_amdgcn_permlane16_swap(xi, xi, false, false);
  return fmaxf(__builtin_bit_cast(float, (unsigned)r[0]),
               __builtin_bit_cast(float, (unsigned)r[1]));
#else
  return fmaxf(x, fshfl_xor(x, 16));
#endif
}
__device__ __forceinline__ float pl16_get(float x, int lane_) {
#if __has_builtin(__builtin_amdgcn_permlane16_swap)
  unsigned xi = __builtin_bit_cast(unsigned, x);
  auto r = __builtin_amdgcn_permlane16_swap(xi, xi, false, false);
  float a = __builtin_bit_cast(float, (unsigned)r[0]);
  float b = __builtin_bit_cast(float, (unsigned)r[1]);
  return (lane_ & 16) ? a : b;   // out0 holds x[i&~16], out1 holds x[i|16]
#else
  return fshfl_xor(x, 16);
#endif
}

// One block = 256 threads = 4 waves, one 32x32 SPD matrix per wave.
// r19 = r18 + launch_bounds(256,7) + sched_barriers in ALL load-heavy loops.
// r18 left us VALU-bound (85%) at 46% occupancy; occupancy tracks the
// waves-per-eu MIN metadata (none/4->46%, 6->67%, 8->87%) but every explicit
// bound so far panic-spilled. Diagnosis: pre-RA load hoisting builds 64-reg
// peaks (T2: 16 f32x4 x-loads; M1: unrolled w1 loads; M2: ~40). bounds-7
// gives budget 73 (+13 slack over natural 60, vs r16's +4) and the barriers
// make >73-reg peaks impossible. Math byte-identical to r18.
// Spill tripwire: WRITE_SIZE ~2.3MB, else r18 stands.
// LDS: 4*1152*4 = 18432 B/block.
#define PT_S 34
__global__ __launch_bounds__(256, 7) void spd_fused(
    const float* __restrict__ xg,
    const float* __restrict__ w1g,
    const float* __restrict__ w2g,
    const float* __restrict__ w3g,
    const float* __restrict__ fcg,
    float* __restrict__ outg,
    int B)
{
  __shared__ float slot[4][1152];

  const int tid  = threadIdx.x;
  const int wid  = tid >> 6;
  const int lane = tid & 63;

  float* Cc = slot[wid];          // x (stride 32) -> M1 cols (stride 36) -> Qb/J scratch
  float* Pt = slot[wid] + 576;    // Ps transposed [16][PT_S], in dead M1 space

  const long b = (long)blockIdx.x * 4 + wid;
  if (b >= B) return;

  // ---------------- load x -> Cc row-major [32][32] (stride 32)
  {
    const f32x4* xv = (const f32x4*)(xg + (size_t)b * 1024);
    f32x4* c4 = (f32x4*)Cc;
    #pragma unroll
    for (int jj = 0; jj < 4; ++jj) {
      int i4 = lane + 64 * jj;
      c4[i4] = xv[i4];
    }
  }
  FENCE();

  const int j = lane & 31;
  const int h = lane >> 5;

  // ---------------- Tmat = x * w1 in registers (packed). T2[e] = rows
  // {16h+2e, +1} of column j. Uses x symmetry: read x rows as f32x4.
  // sched_barrier per iteration: caps in-flight x-row loads at 4 f32x4.
  v2f T2[8];
  {
    #pragma unroll
    for (int e = 0; e < 8; ++e) T2[e] = (v2f){0.f, 0.f};
    const f32x4* c4 = (const f32x4*)Cc;
    #pragma unroll 4
    for (int c = 0; c < 32; ++c) {
      float wv = w1g[c * 32 + j];
      v2f wv2 = {wv, wv};
      f32x4 x0 = c4[c * 8 + h * 4 + 0];
      f32x4 x1 = c4[c * 8 + h * 4 + 1];
      f32x4 x2 = c4[c * 8 + h * 4 + 2];
      f32x4 x3 = c4[c * 8 + h * 4 + 3];
      T2[0] = fma2(x0.lo, wv2, T2[0]); T2[1] = fma2(x0.hi, wv2, T2[1]);
      T2[2] = fma2(x1.lo, wv2, T2[2]); T2[3] = fma2(x1.hi, wv2, T2[3]);
      T2[4] = fma2(x2.lo, wv2, T2[4]); T2[5] = fma2(x2.hi, wv2, T2[5]);
      T2[6] = fma2(x3.lo, wv2, T2[6]); T2[7] = fma2(x3.hi, wv2, T2[7]);
      SBAR();
    }
  }
  FENCE();   // all x reads complete before M1 overwrites Cc

  // ---------------- M1 = w1^T * Tmat -> Cc linear column-major, stride 36.
  // sched_barrier per ih2 quarter: caps hoisted w1 loads.
  {
    const f32x4* w14 = (const f32x4*)w1g;   // row r = w14[r*8 + 0..7]
    #pragma unroll
    for (int ih2 = 0; ih2 < 4; ++ih2) {     // output rows 8*ih2 .. 8*ih2+7
      f32x4 A = {0.f, 0.f, 0.f, 0.f};
      f32x4 Bv = {0.f, 0.f, 0.f, 0.f};
      #pragma unroll
      for (int e = 0; e < 16; ++e) {
        int r = 16 * h + e;
        float tv = T2[e >> 1][e & 1];
        f32x4 tv4 = {tv, tv, tv, tv};
        A  = fma4(w14[r * 8 + ih2 * 2],     tv4, A);
        Bv = fma4(w14[r * 8 + ih2 * 2 + 1], tv4, Bv);
      }
      A.x = pl32_sum(A.x);  A.y = pl32_sum(A.y);
      A.z = pl32_sum(A.z);  A.w = pl32_sum(A.w);
      Bv.x = pl32_sum(Bv.x); Bv.y = pl32_sum(Bv.y);
      Bv.z = pl32_sum(Bv.z); Bv.w = pl32_sum(Bv.w);
      if (h == (ih2 & 1)) {
        *(f32x4*)(Cc + j * 36 + ih2 * 8)     = A;
        *(f32x4*)(Cc + j * 36 + ih2 * 8 + 4) = Bv;
      }
      SBAR();
    }
  }
  FENCE();

  // ---------------- load own column half into v2f registers (one-time)
  v2f v1[8];
  {
    const float* bp = Cc + j * 36 + (h << 4);
    f32x4 q0 = *(const f32x4*)(bp);
    f32x4 q1 = *(const f32x4*)(bp + 4);
    f32x4 q2 = *(const f32x4*)(bp + 8);
    f32x4 q3 = *(const f32x4*)(bp + 12);
    v1[0] = q0.lo; v1[1] = q0.hi; v1[2] = q1.lo; v1[3] = q1.hi;
    v1[4] = q2.lo; v1[5] = q2.hi; v1[6] = q3.lo; v1[7] = q3.hi;
  }

  // ---------------- one-sided Jacobi, n=32, register-resident, XOR
  // tournament (peeled DPP rounds first), incremental norms.
  {
    #define S1ROUND(MVAL, GETF) do {                                       \
      const int m_ = j ^ (MVAL);                                           \
      v2f uu[8];                                                           \
      _Pragma("unroll") for (int i = 0; i < 8; ++i) {                      \
        uu[i].x = GETF(v1[i].x); uu[i].y = GETF(v1[i].y); }                \
      float sb_o = GETF(sn);                                               \
      v2f sgv = {0.f, 0.f};                                                \
      _Pragma("unroll") for (int i = 0; i < 8; ++i)                        \
        sgv = fma2(v1[i], uu[i], sgv);                                     \
      float sg = pl32_sum(sgv.x + sgv.y);                                  \
      const bool isp = j < m_;                                             \
      float nA = isp ? sn : sb_o;                                          \
      float nB = isp ? sb_o : sn;                                          \
      float rel = sg * sg * frcp(fmaxf(nA * nB, 1e-30f));                  \
      offmax = fmaxf(offmax, rel);                                         \
      if (rel > 1e-13f) {                                                  \
        float uc = 0.5f * (nB - nA);                                       \
        float R  = fsqrt(uc * uc + sg * sg);                               \
        float t  = sg * frcp(uc + ((uc >= 0.f) ? R : -R));                 \
        float ct = frsq(1.f + t * t);                                      \
        float st = ct * t;                                                 \
        float s_ = isp ? -st : st;                                         \
        v2f ct2 = {ct, ct}, sv2 = {s_, s_};                                \
        _Pragma("unroll") for (int i = 0; i < 8; ++i)                      \
          v1[i] = fma2(uu[i], sv2, v1[i] * ct2);                           \
        sn = fmaxf(isp ? (nA - t * sg) : (nB + t * sg), 0.f);              \
      }                                                                    \
    } while (0)
    #define G_D1(v)  dppf<DPP_X1>(v)
    #define G_D2(v)  dppf<DPP_X2>(v)
    #define G_D3(v)  dppf<DPP_X3>(v)
    #define G_D7(v)  dppf<DPP_X7>(v)
    #define G_D15(v) dppf<DPP_X15>(v)
    #define G_P16(v) pl16_get(v, lane)
    #define G_RT(v)  fshfl_xor(v, mask)

    #pragma unroll 1
    for (int sweep = 0; sweep < 8; ++sweep) {
      // fresh own-norm (kills incremental drift)
      v2f s2n = {0.f, 0.f};
      #pragma unroll
      for (int i = 0; i < 8; ++i) s2n = fma2(v1[i], v1[i], s2n);
      float sn = pl32_sum(s2n.x + s2n.y);

      float offmax = 0.f;
      // peeled VALU-pipe rounds (DPP / permlane)
      S1ROUND(1,  G_D1);
      S1ROUND(2,  G_D2);
      S1ROUND(3,  G_D3);
      S1ROUND(7,  G_D7);
      S1ROUND(15, G_D15);
      S1ROUND(16, G_P16);
      // remaining masks on the DS pipe
      #pragma unroll 1
      for (int mask = 4; mask < 7; ++mask)   S1ROUND(mask, G_RT);
      #pragma unroll 1
      for (int mask = 8; mask < 15; ++mask)  S1ROUND(mask, G_RT);
      #pragma unroll 1
      for (int mask = 17; mask < 32; ++mask) S1ROUND(mask, G_RT);

      offmax = fmaxf(offmax, dppf<DPP_X1>(offmax));
      offmax = fmaxf(offmax, dppf<DPP_X2>(offmax));
      offmax = fmaxf(offmax, fshfl_xor(offmax, 4));
      offmax = fmaxf(offmax, fshfl_xor(offmax, 8));
      offmax = pl16_max(offmax);
      offmax = pl32_max(offmax);
      if (offmax < 1e-11f) break;
    }
  }

  // ---------------- lambda_1 + ReEig + Ps = sqrt(clamp(lam1))*v1hat^T w2,
  // all from registers; Pt[16][PT_S] transposed (conflict-free).
  // Split halves with sched_barrier: caps the w2-load hoisting spike.
  {
    v2f ssv = {0.f, 0.f};
    #pragma unroll
    for (int i = 0; i < 8; ++i) ssv = fma2(v1[i], v1[i], ssv);
    float ss = pl32_sum(ssv.x + ssv.y);
    float lam = fsqrt(ss);
    float sc1 = (lam > 0.f) ? (fsqrt(fmaxf(lam, 1e-4f)) * frcp(lam)) : 0.f;
    f32x4 acc0 = {0.f,0.f,0.f,0.f}, acc1 = acc0, acc2 = acc0, acc3 = acc0;
    #pragma unroll
    for (int t = 0; t < 4; ++t) {
      int rr = (h << 4) + 2 * t;
      const f32x4* wr0 = (const f32x4*)(w2g + rr * 16);
      const f32x4* wr1 = (const f32x4*)(w2g + (rr + 1) * 16);
      float vx = v1[t].x, vy = v1[t].y;
      f32x4 vx4 = {vx, vx, vx, vx};
      f32x4 vy4 = {vy, vy, vy, vy};
      acc0 = fma4(wr0[0], vx4, acc0); acc1 = fma4(wr0[1], vx4, acc1);
      acc2 = fma4(wr0[2], vx4, acc2); acc3 = fma4(wr0[3], vx4, acc3);
      acc0 = fma4(wr1[0], vy4, acc0); acc1 = fma4(wr1[1], vy4, acc1);
      acc2 = fma4(wr1[2], vy4, acc2); acc3 = fma4(wr1[3], vy4, acc3);
    }
    SBAR();   // don't hoist 2nd-half loads above
    #pragma unroll
    for (int t = 4; t < 8; ++t) {
      int rr = (h << 4) + 2 * t;
      const f32x4* wr0 = (const f32x4*)(w2g + rr * 16);
      const f32x4* wr1 = (const f32x4*)(w2g + (rr + 1) * 16);
      float vx = v1[t].x, vy = v1[t].y;
      f32x4 vx4 = {vx, vx, vx, vx};
      f32x4 vy4 = {vy, vy, vy, vy};
      acc0 = fma4(wr0[0], vx4, acc0); acc1 = fma4(wr0[1], vx4, acc1);
      acc2 = fma4(wr0[2], vx4, acc2); acc3 = fma4(wr0[3], vx4, acc3);
      acc0 = fma4(wr1[0], vy4, acc0); acc1 = fma4(wr1[1], vy4, acc1);
      acc2 = fma4(wr1[2], vy4, acc2); acc3 = fma4(wr1[3], vy4, acc3);
    }
    acc0.x = pl32_sum(acc0.x) * sc1;  acc0.y = pl32_sum(acc0.y) * sc1;
    acc0.z = pl32_sum(acc0.z) * sc1;  acc0.w = pl32_sum(acc0.w) * sc1;
    acc1.x = pl32_sum(acc1.x) * sc1;  acc1.y = pl32_sum(acc1.y) * sc1;
    acc1.z = pl32_sum(acc1.z) * sc1;  acc1.w = pl32_sum(acc1.w) * sc1;
    acc2.x = pl32_sum(acc2.x) * sc1;  acc2.y = pl32_sum(acc2.y) * sc1;
    acc2.z = pl32_sum(acc2.z) * sc1;  acc2.w = pl32_sum(acc2.w) * sc1;
    acc3.x = pl32_sum(acc3.x) * sc1;  acc3.y = pl32_sum(acc3.y) * sc1;
    acc3.z = pl32_sum(acc3.z) * sc1;  acc3.w = pl32_sum(acc3.w) * sc1;
    // lane (j,h) stores Ps[j][8h..8h+7]: h=0 -> acc0/acc1, h=1 -> acc2/acc3
    f32x4 lo = h ? acc2 : acc0;
    f32x4 hi = h ? acc3 : acc1;
    const int jb8 = h << 3;
    Pt[(jb8 + 0) * PT_S + j] = lo.x;
    Pt[(jb8 + 1) * PT_S + j] = lo.y;
    Pt[(jb8 + 2) * PT_S + j] = lo.z;
    Pt[(jb8 + 3) * PT_S + j] = lo.w;
    Pt[(jb8 + 4) * PT_S + j] = hi.x;
    Pt[(jb8 + 5) * PT_S + j] = hi.y;
    Pt[(jb8 + 6) * PT_S + j] = hi.z;
    Pt[(jb8 + 7) * PT_S + j] = hi.w;
  }
  FENCE();

  // ---------------- M2 = Ps^T Ps directly into stage-2 registers.
  // lane = c2 + 16*h4 owns rows 4h4..4h4+3 of M2 column c2.
  // sched_barrier per iteration: caps in-flight Pt loads at 5 f32x4.
  const int c2 = lane & 15;
  const int h4 = lane >> 4;
  f32x4 v2r;
  {
    v2f a0 = {0.f,0.f}, a1 = {0.f,0.f}, a2 = {0.f,0.f}, a3 = {0.f,0.f};
    #pragma unroll 2
    for (int kk = 0; kk < 32; kk += 4) {
      f32x4 aa = *(const f32x4*)(Pt + c2 * PT_S + kk);
      f32x4 b0 = *(const f32x4*)(Pt + (4 * h4 + 0) * PT_S + kk);
      f32x4 b1 = *(const f32x4*)(Pt + (4 * h4 + 1) * PT_S + kk);
      f32x4 b2 = *(const f32x4*)(Pt + (4 * h4 + 2) * PT_S + kk);
      f32x4 b3 = *(const f32x4*)(Pt + (4 * h4 + 3) * PT_S + kk);
      a0 = fma2(aa.lo, b0.lo, a0); a0 = fma2(aa.hi, b0.hi, a0);
      a1 = fma2(aa.lo, b1.lo, a1); a1 = fma2(aa.hi, b1.hi, a1);
      a2 = fma2(aa.lo, b2.lo, a2); a2 = fma2(aa.hi, b2.hi, a2);
      a3 = fma2(aa.lo, b3.lo, a3); a3 = fma2(aa.hi, b3.hi, a3);
      SBAR();
    }
    v2r.x = a0.x + a0.y;
    v2r.y = a1.x + a1.y;
    v2r.z = a2.x + a2.y;
    v2r.w = a3.x + a3.y;
  }

  // ---------------- one-sided Jacobi, n=16, register-resident, XOR
  // tournament (peeled DPP rounds), incremental norms.
  {
    #define S2ROUND(MVAL, GETF) do {                                       \
      const int m_ = c2 ^ (MVAL);                                          \
      float u0 = GETF(v2r.x), u1 = GETF(v2r.y);                            \
      float u2 = GETF(v2r.z), u3 = GETF(v2r.w);                            \
      float sb_o = GETF(sn2);                                              \
      v2f ua = {u0, u1}, ub = {u2, u3};                                    \
      v2f sgv = fma2(v2r.hi, ub, v2r.lo * ua);                             \
      float sg = pl32_sum(pl16_sum(sgv.x + sgv.y));                        \
      const bool isp = c2 < m_;                                            \
      float nA = isp ? sn2 : sb_o;                                         \
      float nB = isp ? sb_o : sn2;                                         \
      float rel = sg * sg * frcp(fmaxf(nA * nB, 1e-30f));                  \
      offmax = fmaxf(offmax, rel);                                         \
      if (rel > 1e-13f) {                                                  \
        float uc = 0.5f * (nB - nA);                                       \
        float R  = fsqrt(uc * uc + sg * sg);                               \
        float t  = sg * frcp(uc + ((uc >= 0.f) ? R : -R));                 \
        float ct = frsq(1.f + t * t);                                      \
        float st = ct * t;                                                 \
        float s_ = isp ? -st : st;                                         \
        f32x4 ct4 = {ct, ct, ct, ct};                                      \
        f32x4 s4  = {s_, s_, s_, s_};                                      \
        f32x4 uu4 = {u0, u1, u2, u3};                                      \
        v2r = fma4(uu4, s4, v2r * ct4);                                    \
        sn2 = fmaxf(isp ? (nA - t * sg) : (nB + t * sg), 0.f);             \
      }                                                                    \
    } while (0)

    #pragma unroll 1
    for (int sweep = 0; sweep < 6; ++sweep) {
      v2f sp = fma2(v2r.hi, v2r.hi, v2r.lo * v2r.lo);
      float sn2 = pl32_sum(pl16_sum(sp.x + sp.y));
      float offmax = 0.f;
      S2ROUND(1,  G_D1);
      S2ROUND(2,  G_D2);
      S2ROUND(3,  G_D3);
      S2ROUND(7,  G_D7);
      S2ROUND(15, G_D15);
      #pragma unroll 1
      for (int mask = 4; mask < 7; ++mask)  S2ROUND(mask, G_RT);
      #pragma unroll 1
      for (int mask = 8; mask < 15; ++mask) S2ROUND(mask, G_RT);

      offmax = fmaxf(offmax, dppf<DPP_X1>(offmax));
      offmax = fmaxf(offmax, dppf<DPP_X2>(offmax));
      offmax = fmaxf(offmax, fshfl_xor(offmax, 4));
      offmax = fmaxf(offmax, fshfl_xor(offmax, 8));
      offmax = pl16_max(offmax);
      offmax = pl32_max(offmax);
      if (offmax < 1e-11f) break;
    }
  }

  // ---------------- Qb row c2 = (V2^T w3)[c2][:] * sqrt(clamp(lam2)) from regs
  {
    f32x4 qq = {0.f, 0.f, 0.f, 0.f};
    f32x4 w0 = *(const f32x4*)(w3g + (4 * h4 + 0) * 4);
    f32x4 w1r = *(const f32x4*)(w3g + (4 * h4 + 1) * 4);
    f32x4 w2r = *(const f32x4*)(w3g + (4 * h4 + 2) * 4);
    f32x4 w3r = *(const f32x4*)(w3g + (4 * h4 + 3) * 4);
    f32x4 vv0 = {v2r.x, v2r.x, v2r.x, v2r.x};
    f32x4 vv1 = {v2r.y, v2r.y, v2r.y, v2r.y};
    f32x4 vv2 = {v2r.z, v2r.z, v2r.z, v2r.z};
    f32x4 vv3 = {v2r.w, v2r.w, v2r.w, v2r.w};
    qq = fma4(w0, vv0, qq); qq = fma4(w1r, vv1, qq);
    qq = fma4(w2r, vv2, qq); qq = fma4(w3r, vv3, qq);
    v2f sp = fma2(v2r.hi, v2r.hi, v2r.lo * v2r.lo);
    float ssp = sp.x + sp.y;
    float q0 = pl32_sum(pl16_sum(qq.x));
    float q1 = pl32_sum(pl16_sum(qq.y));
    float q2 = pl32_sum(pl16_sum(qq.z));
    float q3 = pl32_sum(pl16_sum(qq.w));
    ssp = pl32_sum(pl16_sum(ssp));
    float lam = fsqrt(ssp);
    float scl = (lam > 0.f) ? (frcp(lam) * fsqrt(fmaxf(lam, 1e-4f))) : 0.f;
    if (h4 == 0)
      *(f32x4*)(Cc + c2 * 4) = (f32x4){q0 * scl, q1 * scl, q2 * scl, q3 * scl};
  }
  FENCE();

  // ---------------- stage 3: one-sided Jacobi ON THE 16x4 FACTOR, with
  // accumulated rotations J (eigenvectors of M3 = Q^T Q). 5 sweeps.
  // All ROT3 exchange masks are in {1,2,3} -> DPP; 16/32 reduces -> permlane.
  float qv = Cc[lane];            // Qb[kq][jq], kq*4+jq == lane
  const int kq = lane >> 2;
  const int jq = lane & 3;
  float jv = (kq == jq) ? 1.f : 0.f;
  {
    #define ROT3(P_, Q_, DC_) do {                                        \
      float w_ = dppf<DC_>(qv);                                           \
      float s1 = qv * qv, s2 = w_ * w_, s3 = qv * w_;                     \
      s1 += fshfl_xor(s1, 4);  s2 += fshfl_xor(s2, 4);  s3 += fshfl_xor(s3, 4); \
      s1 += fshfl_xor(s1, 8);  s2 += fshfl_xor(s2, 8);  s3 += fshfl_xor(s3, 8); \
      s1 = pl16_sum(s1); s2 = pl16_sum(s2); s3 = pl16_sum(s3);            \
      s1 = pl32_sum(s1); s2 = pl32_sum(s2); s3 = pl32_sum(s3);            \
      bool isp = (jq == (P_)), isq = (jq == (Q_));                        \
      float sa = isp ? s1 : s2;                                           \
      float sb = isp ? s2 : s1;                                           \
      float u_ = 0.5f * (sb - sa);                                        \
      float R_ = fsqrt(u_ * u_ + s3 * s3);                                \
      float dn_ = u_ + copysignf(fmaxf(R_, 1e-30f), u_);                  \
      float t_ = s3 * frcp(dn_);                                          \
      float ct = frsq(1.f + t_ * t_);                                     \
      float st = ct * t_;                                                 \
      float wj_ = dppf<DC_>(jv);                                          \
      float nv  = isp ? (ct * qv - st * w_)  : (st * w_  + ct * qv);      \
      float nvj = isp ? (ct * jv - st * wj_) : (st * wj_ + ct * jv);      \
      if (isp | isq) { qv = nv; jv = nvj; }                               \
    } while (0)

    #pragma unroll 1
    for (int sweep = 0; sweep < 5; ++sweep) {
      ROT3(0,1,DPP_X1); ROT3(2,3,DPP_X1);
      ROT3(0,2,DPP_X2); ROT3(1,3,DPP_X2);
      ROT3(0,3,DPP_X3); ROT3(1,2,DPP_X3);
    }
    #undef ROT3
  }

  // ---------------- lambda_3 = ||col||^2, LogEig via J, FC, log_softmax
  {
    float ss = qv * qv;
    ss += fshfl_xor(ss, 4); ss += fshfl_xor(ss, 8);
    ss = pl16_sum(ss); ss = pl32_sum(ss);
    float lwv = logf(fmaxf(ss, 1e-10f));       // log eigenvalue of column jq
    if (kq < 4)  Cc[64 + kq * 4 + jq] = jv;    // J, row-major 4x4
    if (kq == 0) Cc[80 + jq] = lwv;            // lanes 0..3: per-column loglam
    FENCE();

    float f = 0.f;
    if (lane < 16) {
      int i3 = lane >> 2, j3 = lane & 3;
      #pragma unroll
      for (int c = 0; c < 4; ++c)
        f += Cc[80 + c] * Cc[64 + i3 * 4 + c] * Cc[64 + j3 * 4 + c];
    }
    float t0 = 0.f, t1 = 0.f;
    if (lane < 16) { t0 = f * fcg[2 * lane]; t1 = f * fcg[2 * lane + 1]; }
    t0 += dppf<DPP_X1>(t0); t1 += dppf<DPP_X1>(t1);
    t0 += dppf<DPP_X2>(t0); t1 += dppf<DPP_X2>(t1);
    t0 += fshfl_xor(t0, 4); t1 += fshfl_xor(t1, 4);
    t0 += fshfl_xor(t0, 8); t1 += fshfl_xor(t1, 8);
    float mx  = fmaxf(t0, t1);
    float lse = mx + logf(expf(t0 - mx) + expf(t1 - mx));

    float* outFeat = outg + (size_t)B * 2;
    if (lane < 16) outFeat[(size_t)b * 16 + lane] = f;
    if (lane < 2)  outg[(size_t)b * 2 + lane] = (lane == 0 ? t0 : t1) - lse;
  }
}

extern "C" void kernel_launch(void* const* d_in, const int* in_sizes, int n_in,
                              void* d_out, int out_size, void* d_ws, size_t ws_size,
                              hipStream_t stream) {
  const float* x  = (const float*)d_in[0];
  const float* w1 = (const float*)d_in[1];
  const float* w2 = (const float*)d_in[2];
  const float* w3 = (const float*)d_in[3];
  const float* fc = (const float*)d_in[4];
  float* out = (float*)d_out;
  int B = in_sizes[0] / 1024;
  int grid = (B + 3) / 4;
  hipLaunchKernelGGL(spd_fused, dim3(grid), dim3(256), 0, stream,
                     x, w1, w2, w3, fc, out, B);
}

// Round 20
// 1446.709 us; speedup vs baseline: 1.4321x; 1.1293x over previous
//
#include <hip/hip_runtime.h>

// Wave-level LDS ordering fence for the few remaining LDS phase transitions.
#define FENCE() asm volatile("s_waitcnt lgkmcnt(0)" ::: "memory")

typedef float v2f   __attribute__((ext_vector_type(2)));
typedef float f32x4 __attribute__((ext_vector_type(4)));

__device__ __forceinline__ float fshfl_xor(float v, int m) { return __shfl_xor(v, m, 64); }
__device__ __forceinline__ float fsqrt(float x) { return __builtin_amdgcn_sqrtf(x); }
__device__ __forceinline__ float frcp (float x) { return __builtin_amdgcn_rcpf(x); }
__device__ __forceinline__ float frsq (float x) { return __builtin_amdgcn_rsqf(x); }
__device__ __forceinline__ v2f   fma2(v2f a, v2f b, v2f c)       { return __builtin_elementwise_fma(a, b, c); }
__device__ __forceinline__ f32x4 fma4(f32x4 a, f32x4 b, f32x4 c) { return __builtin_elementwise_fma(a, b, c); }

// ---- VALU-pipe lane exchange (r18, validated: dur 2030->1641).
// r19 post-mortem: dur tracks DS-round count exactly (r17->r18 ratio 0.794
// vs 25/31=0.806) -> still DS-pipe-bound. Pipe-balance model says shifting
// ~2 more rounds DS->VALU (composed masks) reaches balance (~1510).
template<int C>
__device__ __forceinline__ float dppf(float x) {
  return __builtin_bit_cast(float,
      __builtin_amdgcn_mov_dpp(__builtin_bit_cast(int, x), C, 0xF, 0xF, true));
}
#define DPP_X1  0xB1   // quad_perm [1,0,3,2]
#define DPP_X2  0x4E   // quad_perm [2,3,0,1]
#define DPP_X3  0x1B   // quad_perm [3,2,1,0]
#define DPP_X7  0x141  // row_half_mirror
#define DPP_X15 0x140  // row_mirror

__device__ __forceinline__ float pl32_sum(float x) {
#if __has_builtin(__builtin_amdgcn_permlane32_swap)
  unsigned xi = __builtin_bit_cast(unsigned, x);
  auto r = __builtin_amdgcn_permlane32_swap(xi, xi, false, false);
  return __builtin_bit_cast(float, (unsigned)r[0]) +
         __builtin_bit_cast(float, (unsigned)r[1]);
#else
  return x + fshfl_xor(x, 32);
#endif
}
__device__ __forceinline__ float pl32_max(float x) {
#if __has_builtin(__builtin_amdgcn_permlane32_swap)
  unsigned xi = __builtin_bit_cast(unsigned, x);
  auto r = __builtin_amdgcn_permlane32_swap(xi, xi, false, false);
  return fmaxf(__builtin_bit_cast(float, (unsigned)r[0]),
               __builtin_bit_cast(float, (unsigned)r[1]));
#else
  return fmaxf(x, fshfl_xor(x, 32));
#endif
}
__device__ __forceinline__ float pl16_sum(float x) {
#if __has_builtin(__builtin_amdgcn_permlane16_swap)
  unsigned xi = __builtin_bit_cast(unsigned, x);
  auto r = __builtin_amdgcn_permlane16_swap(xi, xi, false, false);
  return __builtin_bit_cast(float, (unsigned)r[0]) +
         __builtin_bit_cast(float, (unsigned)r[1]);
#else
  return x + fshfl_xor(x, 16);
#endif
}
__device__ __forceinline__ float pl16_max(float x) {
#if __has_builtin(__builtin_amdgcn_permlane16_swap)
  unsigned xi = __builtin_bit_cast(unsigned, x);
  auto r = __builtin_amdgcn_permlane16_swap(xi, xi, false, false);
  return fmaxf(__builtin_bit_cast(float, (unsigned)r[0]),
               __builtin_bit_cast(float, (unsigned)r[1]));
#else
  return fmaxf(x, fshfl_xor(x, 16));
#endif
}
__device__ __forceinline__ float pl16_get(float x, int lane_) {
#if __has_builtin(__builtin_amdgcn_permlane16_swap)
  unsigned xi = __builtin_bit_cast(unsigned, x);
  auto r = __builtin_amdgcn_permlane16_swap(xi, xi, false, false);
  float a = __builtin_bit_cast(float, (unsigned)r[0]);
  float b = __builtin_bit_cast(float, (unsigned)r[1]);
  return (lane_ & 16) ? a : b;   // out0 holds x[i&~16], out1 holds x[i|16]
#else
  return fshfl_xor(x, 16);
#endif
}

// One block = 256 threads = 4 waves, one 32x32 SPD matrix per wave.
// r20 = r18 (clean, no launch_bounds -- 6 explicit-bounds attempts all
// panic-spilled; axis abandoned) + two cuts:
//  1. masks 17,18 -> VALU via composition pl16_get(dpp_x1/x2(v)) (xor17 =
//     xor1*xor16; both primitives validated r18). DS rounds 25 -> 23;
//     pipe-balance model (T_DS 1641 vs T_VALU 1395, -17DS/+51VALU per
//     shifted round) says ~2 rounds is the balance point.
//  2. sweep trim (scales both pipes): stage-1 cap 8->7 exit 1e-10,
//     stage-2 cap 6->5 exit 1e-10 (off-angle <1e-5, harmless vs 0.75 abs).
// Spill tripwire: WRITE_SIZE ~2.3MB. LDS: 4*1152*4 = 18432 B/block.
#define PT_S 34
__global__ __launch_bounds__(256) void spd_fused(
    const float* __restrict__ xg,
    const float* __restrict__ w1g,
    const float* __restrict__ w2g,
    const float* __restrict__ w3g,
    const float* __restrict__ fcg,
    float* __restrict__ outg,
    int B)
{
  __shared__ float slot[4][1152];

  const int tid  = threadIdx.x;
  const int wid  = tid >> 6;
  const int lane = tid & 63;

  float* Cc = slot[wid];          // x (stride 32) -> M1 cols (stride 36) -> Qb/J scratch
  float* Pt = slot[wid] + 576;    // Ps transposed [16][PT_S], in dead M1 space

  const long b = (long)blockIdx.x * 4 + wid;
  if (b >= B) return;

  // ---------------- load x -> Cc row-major [32][32] (stride 32)
  {
    const f32x4* xv = (const f32x4*)(xg + (size_t)b * 1024);
    f32x4* c4 = (f32x4*)Cc;
    #pragma unroll
    for (int jj = 0; jj < 4; ++jj) {
      int i4 = lane + 64 * jj;
      c4[i4] = xv[i4];
    }
  }
  FENCE();

  const int j = lane & 31;
  const int h = lane >> 5;

  // ---------------- Tmat = x * w1 in registers (packed). T2[e] = rows
  // {16h+2e, +1} of column j. Uses x symmetry: read x rows as f32x4.
  v2f T2[8];
  {
    #pragma unroll
    for (int e = 0; e < 8; ++e) T2[e] = (v2f){0.f, 0.f};
    const f32x4* c4 = (const f32x4*)Cc;
    #pragma unroll 4
    for (int c = 0; c < 32; ++c) {
      float wv = w1g[c * 32 + j];
      v2f wv2 = {wv, wv};
      f32x4 x0 = c4[c * 8 + h * 4 + 0];
      f32x4 x1 = c4[c * 8 + h * 4 + 1];
      f32x4 x2 = c4[c * 8 + h * 4 + 2];
      f32x4 x3 = c4[c * 8 + h * 4 + 3];
      T2[0] = fma2(x0.lo, wv2, T2[0]); T2[1] = fma2(x0.hi, wv2, T2[1]);
      T2[2] = fma2(x1.lo, wv2, T2[2]); T2[3] = fma2(x1.hi, wv2, T2[3]);
      T2[4] = fma2(x2.lo, wv2, T2[4]); T2[5] = fma2(x2.hi, wv2, T2[5]);
      T2[6] = fma2(x3.lo, wv2, T2[6]); T2[7] = fma2(x3.hi, wv2, T2[7]);
    }
  }
  FENCE();   // all x reads complete before M1 overwrites Cc

  // ---------------- M1 = w1^T * Tmat -> Cc linear column-major, stride 36.
  {
    const f32x4* w14 = (const f32x4*)w1g;   // row r = w14[r*8 + 0..7]
    #pragma unroll
    for (int ih2 = 0; ih2 < 4; ++ih2) {     // output rows 8*ih2 .. 8*ih2+7
      f32x4 A = {0.f, 0.f, 0.f, 0.f};
      f32x4 Bv = {0.f, 0.f, 0.f, 0.f};
      #pragma unroll
      for (int e = 0; e < 16; ++e) {
        int r = 16 * h + e;
        float tv = T2[e >> 1][e & 1];
        f32x4 tv4 = {tv, tv, tv, tv};
        A  = fma4(w14[r * 8 + ih2 * 2],     tv4, A);
        Bv = fma4(w14[r * 8 + ih2 * 2 + 1], tv4, Bv);
      }
      A.x = pl32_sum(A.x);  A.y = pl32_sum(A.y);
      A.z = pl32_sum(A.z);  A.w = pl32_sum(A.w);
      Bv.x = pl32_sum(Bv.x); Bv.y = pl32_sum(Bv.y);
      Bv.z = pl32_sum(Bv.z); Bv.w = pl32_sum(Bv.w);
      if (h == (ih2 & 1)) {
        *(f32x4*)(Cc + j * 36 + ih2 * 8)     = A;
        *(f32x4*)(Cc + j * 36 + ih2 * 8 + 4) = Bv;
      }
    }
  }
  FENCE();

  // ---------------- load own column half into v2f registers (one-time)
  v2f v1[8];
  {
    const float* bp = Cc + j * 36 + (h << 4);
    f32x4 q0 = *(const f32x4*)(bp);
    f32x4 q1 = *(const f32x4*)(bp + 4);
    f32x4 q2 = *(const f32x4*)(bp + 8);
    f32x4 q3 = *(const f32x4*)(bp + 12);
    v1[0] = q0.lo; v1[1] = q0.hi; v1[2] = q1.lo; v1[3] = q1.hi;
    v1[4] = q2.lo; v1[5] = q2.hi; v1[6] = q3.lo; v1[7] = q3.hi;
  }

  // ---------------- one-sided Jacobi, n=32, register-resident, XOR
  // tournament (peeled VALU rounds first), incremental norms.
  {
    #define S1ROUND(MVAL, GETF) do {                                       \
      const int m_ = j ^ (MVAL);                                           \
      v2f uu[8];                                                           \
      _Pragma("unroll") for (int i = 0; i < 8; ++i) {                      \
        uu[i].x = GETF(v1[i].x); uu[i].y = GETF(v1[i].y); }                \
      float sb_o = GETF(sn);                                               \
      v2f sgv = {0.f, 0.f};                                                \
      _Pragma("unroll") for (int i = 0; i < 8; ++i)                        \
        sgv = fma2(v1[i], uu[i], sgv);                                     \
      float sg = pl32_sum(sgv.x + sgv.y);                                  \
      const bool isp = j < m_;                                             \
      float nA = isp ? sn : sb_o;                                          \
      float nB = isp ? sb_o : sn;                                          \
      float rel = sg * sg * frcp(fmaxf(nA * nB, 1e-30f));                  \
      offmax = fmaxf(offmax, rel);                                         \
      if (rel > 1e-13f) {                                                  \
        float uc = 0.5f * (nB - nA);                                       \
        float R  = fsqrt(uc * uc + sg * sg);                               \
        float t  = sg * frcp(uc + ((uc >= 0.f) ? R : -R));                 \
        float ct = frsq(1.f + t * t);                                      \
        float st = ct * t;                                                 \
        float s_ = isp ? -st : st;                                         \
        v2f ct2 = {ct, ct}, sv2 = {s_, s_};                                \
        _Pragma("unroll") for (int i = 0; i < 8; ++i)                      \
          v1[i] = fma2(uu[i], sv2, v1[i] * ct2);                           \
        sn = fmaxf(isp ? (nA - t * sg) : (nB + t * sg), 0.f);              \
      }                                                                    \
    } while (0)
    #define G_D1(v)  dppf<DPP_X1>(v)
    #define G_D2(v)  dppf<DPP_X2>(v)
    #define G_D3(v)  dppf<DPP_X3>(v)
    #define G_D7(v)  dppf<DPP_X7>(v)
    #define G_D15(v) dppf<DPP_X15>(v)
    #define G_P16(v) pl16_get(v, lane)
    #define G_C17(v) pl16_get(dppf<DPP_X1>(v), lane)   // xor17 = xor1*xor16
    #define G_C18(v) pl16_get(dppf<DPP_X2>(v), lane)   // xor18 = xor2*xor16
    #define G_RT(v)  fshfl_xor(v, mask)

    #pragma unroll 1
    for (int sweep = 0; sweep < 7; ++sweep) {
      // fresh own-norm (kills incremental drift)
      v2f s2n = {0.f, 0.f};
      #pragma unroll
      for (int i = 0; i < 8; ++i) s2n = fma2(v1[i], v1[i], s2n);
      float sn = pl32_sum(s2n.x + s2n.y);

      float offmax = 0.f;
      // peeled VALU-pipe rounds (DPP / permlane / composed)
      S1ROUND(1,  G_D1);
      S1ROUND(2,  G_D2);
      S1ROUND(3,  G_D3);
      S1ROUND(7,  G_D7);
      S1ROUND(15, G_D15);
      S1ROUND(16, G_P16);
      S1ROUND(17, G_C17);
      S1ROUND(18, G_C18);
      // remaining masks on the DS pipe
      #pragma unroll 1
      for (int mask = 4; mask < 7; ++mask)   S1ROUND(mask, G_RT);
      #pragma unroll 1
      for (int mask = 8; mask < 15; ++mask)  S1ROUND(mask, G_RT);
      #pragma unroll 1
      for (int mask = 19; mask < 32; ++mask) S1ROUND(mask, G_RT);

      offmax = fmaxf(offmax, dppf<DPP_X1>(offmax));
      offmax = fmaxf(offmax, dppf<DPP_X2>(offmax));
      offmax = fmaxf(offmax, fshfl_xor(offmax, 4));
      offmax = fmaxf(offmax, fshfl_xor(offmax, 8));
      offmax = pl16_max(offmax);
      offmax = pl32_max(offmax);
      if (offmax < 1e-10f) break;
    }
  }

  // ---------------- lambda_1 + ReEig + Ps = sqrt(clamp(lam1))*v1hat^T w2,
  // all from registers; Pt[16][PT_S] transposed (conflict-free).
  // Split halves with sched_barrier: caps the w2-load hoisting spike.
  {
    v2f ssv = {0.f, 0.f};
    #pragma unroll
    for (int i = 0; i < 8; ++i) ssv = fma2(v1[i], v1[i], ssv);
    float ss = pl32_sum(ssv.x + ssv.y);
    float lam = fsqrt(ss);
    float sc1 = (lam > 0.f) ? (fsqrt(fmaxf(lam, 1e-4f)) * frcp(lam)) : 0.f;
    f32x4 acc0 = {0.f,0.f,0.f,0.f}, acc1 = acc0, acc2 = acc0, acc3 = acc0;
    #pragma unroll
    for (int t = 0; t < 4; ++t) {
      int rr = (h << 4) + 2 * t;
      const f32x4* wr0 = (const f32x4*)(w2g + rr * 16);
      const f32x4* wr1 = (const f32x4*)(w2g + (rr + 1) * 16);
      float vx = v1[t].x, vy = v1[t].y;
      f32x4 vx4 = {vx, vx, vx, vx};
      f32x4 vy4 = {vy, vy, vy, vy};
      acc0 = fma4(wr0[0], vx4, acc0); acc1 = fma4(wr0[1], vx4, acc1);
      acc2 = fma4(wr0[2], vx4, acc2); acc3 = fma4(wr0[3], vx4, acc3);
      acc0 = fma4(wr1[0], vy4, acc0); acc1 = fma4(wr1[1], vy4, acc1);
      acc2 = fma4(wr1[2], vy4, acc2); acc3 = fma4(wr1[3], vy4, acc3);
    }
    __builtin_amdgcn_sched_barrier(0);   // don't hoist 2nd-half loads above
    #pragma unroll
    for (int t = 4; t < 8; ++t) {
      int rr = (h << 4) + 2 * t;
      const f32x4* wr0 = (const f32x4*)(w2g + rr * 16);
      const f32x4* wr1 = (const f32x4*)(w2g + (rr + 1) * 16);
      float vx = v1[t].x, vy = v1[t].y;
      f32x4 vx4 = {vx, vx, vx, vx};
      f32x4 vy4 = {vy, vy, vy, vy};
      acc0 = fma4(wr0[0], vx4, acc0); acc1 = fma4(wr0[1], vx4, acc1);
      acc2 = fma4(wr0[2], vx4, acc2); acc3 = fma4(wr0[3], vx4, acc3);
      acc0 = fma4(wr1[0], vy4, acc0); acc1 = fma4(wr1[1], vy4, acc1);
      acc2 = fma4(wr1[2], vy4, acc2); acc3 = fma4(wr1[3], vy4, acc3);
    }
    acc0.x = pl32_sum(acc0.x) * sc1;  acc0.y = pl32_sum(acc0.y) * sc1;
    acc0.z = pl32_sum(acc0.z) * sc1;  acc0.w = pl32_sum(acc0.w) * sc1;
    acc1.x = pl32_sum(acc1.x) * sc1;  acc1.y = pl32_sum(acc1.y) * sc1;
    acc1.z = pl32_sum(acc1.z) * sc1;  acc1.w = pl32_sum(acc1.w) * sc1;
    acc2.x = pl32_sum(acc2.x) * sc1;  acc2.y = pl32_sum(acc2.y) * sc1;
    acc2.z = pl32_sum(acc2.z) * sc1;  acc2.w = pl32_sum(acc2.w) * sc1;
    acc3.x = pl32_sum(acc3.x) * sc1;  acc3.y = pl32_sum(acc3.y) * sc1;
    acc3.z = pl32_sum(acc3.z) * sc1;  acc3.w = pl32_sum(acc3.w) * sc1;
    // lane (j,h) stores Ps[j][8h..8h+7]: h=0 -> acc0/acc1, h=1 -> acc2/acc3
    f32x4 lo = h ? acc2 : acc0;
    f32x4 hi = h ? acc3 : acc1;
    const int jb8 = h << 3;
    Pt[(jb8 + 0) * PT_S + j] = lo.x;
    Pt[(jb8 + 1) * PT_S + j] = lo.y;
    Pt[(jb8 + 2) * PT_S + j] = lo.z;
    Pt[(jb8 + 3) * PT_S + j] = lo.w;
    Pt[(jb8 + 4) * PT_S + j] = hi.x;
    Pt[(jb8 + 5) * PT_S + j] = hi.y;
    Pt[(jb8 + 6) * PT_S + j] = hi.z;
    Pt[(jb8 + 7) * PT_S + j] = hi.w;
  }
  FENCE();

  // ---------------- M2 = Ps^T Ps directly into stage-2 registers.
  // lane = c2 + 16*h4 owns rows 4h4..4h4+3 of M2 column c2.
  const int c2 = lane & 15;
  const int h4 = lane >> 4;
  f32x4 v2r;
  {
    v2f a0 = {0.f,0.f}, a1 = {0.f,0.f}, a2 = {0.f,0.f}, a3 = {0.f,0.f};
    #pragma unroll 2
    for (int kk = 0; kk < 32; kk += 4) {
      f32x4 aa = *(const f32x4*)(Pt + c2 * PT_S + kk);
      f32x4 b0 = *(const f32x4*)(Pt + (4 * h4 + 0) * PT_S + kk);
      f32x4 b1 = *(const f32x4*)(Pt + (4 * h4 + 1) * PT_S + kk);
      f32x4 b2 = *(const f32x4*)(Pt + (4 * h4 + 2) * PT_S + kk);
      f32x4 b3 = *(const f32x4*)(Pt + (4 * h4 + 3) * PT_S + kk);
      a0 = fma2(aa.lo, b0.lo, a0); a0 = fma2(aa.hi, b0.hi, a0);
      a1 = fma2(aa.lo, b1.lo, a1); a1 = fma2(aa.hi, b1.hi, a1);
      a2 = fma2(aa.lo, b2.lo, a2); a2 = fma2(aa.hi, b2.hi, a2);
      a3 = fma2(aa.lo, b3.lo, a3); a3 = fma2(aa.hi, b3.hi, a3);
    }
    v2r.x = a0.x + a0.y;
    v2r.y = a1.x + a1.y;
    v2r.z = a2.x + a2.y;
    v2r.w = a3.x + a3.y;
  }

  // ---------------- one-sided Jacobi, n=16, register-resident, XOR
  // tournament (peeled DPP rounds), incremental norms.
  {
    #define S2ROUND(MVAL, GETF) do {                                       \
      const int m_ = c2 ^ (MVAL);                                          \
      float u0 = GETF(v2r.x), u1 = GETF(v2r.y);                            \
      float u2 = GETF(v2r.z), u3 = GETF(v2r.w);                            \
      float sb_o = GETF(sn2);                                              \
      v2f ua = {u0, u1}, ub = {u2, u3};                                    \
      v2f sgv = fma2(v2r.hi, ub, v2r.lo * ua);                             \
      float sg = pl32_sum(pl16_sum(sgv.x + sgv.y));                        \
      const bool isp = c2 < m_;                                            \
      float nA = isp ? sn2 : sb_o;                                         \
      float nB = isp ? sb_o : sn2;                                         \
      float rel = sg * sg * frcp(fmaxf(nA * nB, 1e-30f));                  \
      offmax = fmaxf(offmax, rel);                                         \
      if (rel > 1e-13f) {                                                  \
        float uc = 0.5f * (nB - nA);                                       \
        float R  = fsqrt(uc * uc + sg * sg);                               \
        float t  = sg * frcp(uc + ((uc >= 0.f) ? R : -R));                 \
        float ct = frsq(1.f + t * t);                                      \
        float st = ct * t;                                                 \
        float s_ = isp ? -st : st;                                         \
        f32x4 ct4 = {ct, ct, ct, ct};                                      \
        f32x4 s4  = {s_, s_, s_, s_};                                      \
        f32x4 uu4 = {u0, u1, u2, u3};                                      \
        v2r = fma4(uu4, s4, v2r * ct4);                                    \
        sn2 = fmaxf(isp ? (nA - t * sg) : (nB + t * sg), 0.f);             \
      }                                                                    \
    } while (0)

    #pragma unroll 1
    for (int sweep = 0; sweep < 5; ++sweep) {
      v2f sp = fma2(v2r.hi, v2r.hi, v2r.lo * v2r.lo);
      float sn2 = pl32_sum(pl16_sum(sp.x + sp.y));
      float offmax = 0.f;
      S2ROUND(1,  G_D1);
      S2ROUND(2,  G_D2);
      S2ROUND(3,  G_D3);
      S2ROUND(7,  G_D7);
      S2ROUND(15, G_D15);
      #pragma unroll 1
      for (int mask = 4; mask < 7; ++mask)  S2ROUND(mask, G_RT);
      #pragma unroll 1
      for (int mask = 8; mask < 15; ++mask) S2ROUND(mask, G_RT);

      offmax = fmaxf(offmax, dppf<DPP_X1>(offmax));
      offmax = fmaxf(offmax, dppf<DPP_X2>(offmax));
      offmax = fmaxf(offmax, fshfl_xor(offmax, 4));
      offmax = fmaxf(offmax, fshfl_xor(offmax, 8));
      offmax = pl16_max(offmax);
      offmax = pl32_max(offmax);
      if (offmax < 1e-10f) break;
    }
  }

  // ---------------- Qb row c2 = (V2^T w3)[c2][:] * sqrt(clamp(lam2)) from regs
  {
    f32x4 qq = {0.f, 0.f, 0.f, 0.f};
    f32x4 w0 = *(const f32x4*)(w3g + (4 * h4 + 0) * 4);
    f32x4 w1r = *(const f32x4*)(w3g + (4 * h4 + 1) * 4);
    f32x4 w2r = *(const f32x4*)(w3g + (4 * h4 + 2) * 4);
    f32x4 w3r = *(const f32x4*)(w3g + (4 * h4 + 3) * 4);
    f32x4 vv0 = {v2r.x, v2r.x, v2r.x, v2r.x};
    f32x4 vv1 = {v2r.y, v2r.y, v2r.y, v2r.y};
    f32x4 vv2 = {v2r.z, v2r.z, v2r.z, v2r.z};
    f32x4 vv3 = {v2r.w, v2r.w, v2r.w, v2r.w};
    qq = fma4(w0, vv0, qq); qq = fma4(w1r, vv1, qq);
    qq = fma4(w2r, vv2, qq); qq = fma4(w3r, vv3, qq);
    v2f sp = fma2(v2r.hi, v2r.hi, v2r.lo * v2r.lo);
    float ssp = sp.x + sp.y;
    float q0 = pl32_sum(pl16_sum(qq.x));
    float q1 = pl32_sum(pl16_sum(qq.y));
    float q2 = pl32_sum(pl16_sum(qq.z));
    float q3 = pl32_sum(pl16_sum(qq.w));
    ssp = pl32_sum(pl16_sum(ssp));
    float lam = fsqrt(ssp);
    float scl = (lam > 0.f) ? (frcp(lam) * fsqrt(fmaxf(lam, 1e-4f))) : 0.f;
    if (h4 == 0)
      *(f32x4*)(Cc + c2 * 4) = (f32x4){q0 * scl, q1 * scl, q2 * scl, q3 * scl};
  }
  FENCE();

  // ---------------- stage 3: one-sided Jacobi ON THE 16x4 FACTOR, with
  // accumulated rotations J (eigenvectors of M3 = Q^T Q). 5 sweeps.
  float qv = Cc[lane];            // Qb[kq][jq], kq*4+jq == lane
  const int kq = lane >> 2;
  const int jq = lane & 3;
  float jv = (kq == jq) ? 1.f : 0.f;
  {
    #define ROT3(P_, Q_, DC_) do {                                        \
      float w_ = dppf<DC_>(qv);                                           \
      float s1 = qv * qv, s2 = w_ * w_, s3 = qv * w_;                     \
      s1 += fshfl_xor(s1, 4);  s2 += fshfl_xor(s2, 4);  s3 += fshfl_xor(s3, 4); \
      s1 += fshfl_xor(s1, 8);  s2 += fshfl_xor(s2, 8);  s3 += fshfl_xor(s3, 8); \
      s1 = pl16_sum(s1); s2 = pl16_sum(s2); s3 = pl16_sum(s3);            \
      s1 = pl32_sum(s1); s2 = pl32_sum(s2); s3 = pl32_sum(s3);            \
      bool isp = (jq == (P_)), isq = (jq == (Q_));                        \
      float sa = isp ? s1 : s2;                                           \
      float sb = isp ? s2 : s1;                                           \
      float u_ = 0.5f * (sb - sa);                                        \
      float R_ = fsqrt(u_ * u_ + s3 * s3);                                \
      float dn_ = u_ + copysignf(fmaxf(R_, 1e-30f), u_);                  \
      float t_ = s3 * frcp(dn_);                                          \
      float ct = frsq(1.f + t_ * t_);                                     \
      float st = ct * t_;                                                 \
      float wj_ = dppf<DC_>(jv);                                          \
      float nv  = isp ? (ct * qv - st * w_)  : (st * w_  + ct * qv);      \
      float nvj = isp ? (ct * jv - st * wj_) : (st * wj_ + ct * jv);      \
      if (isp | isq) { qv = nv; jv = nvj; }                               \
    } while (0)

    #pragma unroll 1
    for (int sweep = 0; sweep < 5; ++sweep) {
      ROT3(0,1,DPP_X1); ROT3(2,3,DPP_X1);
      ROT3(0,2,DPP_X2); ROT3(1,3,DPP_X2);
      ROT3(0,3,DPP_X3); ROT3(1,2,DPP_X3);
    }
    #undef ROT3
  }

  // ---------------- lambda_3 = ||col||^2, LogEig via J, FC, log_softmax
  {
    float ss = qv * qv;
    ss += fshfl_xor(ss, 4); ss += fshfl_xor(ss, 8);
    ss = pl16_sum(ss); ss = pl32_sum(ss);
    float lwv = logf(fmaxf(ss, 1e-10f));       // log eigenvalue of column jq
    if (kq < 4)  Cc[64 + kq * 4 + jq] = jv;    // J, row-major 4x4
    if (kq == 0) Cc[80 + jq] = lwv;            // lanes 0..3: per-column loglam
    FENCE();

    float f = 0.f;
    if (lane < 16) {
      int i3 = lane >> 2, j3 = lane & 3;
      #pragma unroll
      for (int c = 0; c < 4; ++c)
        f += Cc[80 + c] * Cc[64 + i3 * 4 + c] * Cc[64 + j3 * 4 + c];
    }
    float t0 = 0.f, t1 = 0.f;
    if (lane < 16) { t0 = f * fcg[2 * lane]; t1 = f * fcg[2 * lane + 1]; }
    t0 += dppf<DPP_X1>(t0); t1 += dppf<DPP_X1>(t1);
    t0 += dppf<DPP_X2>(t0); t1 += dppf<DPP_X2>(t1);
    t0 += fshfl_xor(t0, 4); t1 += fshfl_xor(t1, 4);
    t0 += fshfl_xor(t0, 8); t1 += fshfl_xor(t1, 8);
    float mx  = fmaxf(t0, t1);
    float lse = mx + logf(expf(t0 - mx) + expf(t1 - mx));

    float* outFeat = outg + (size_t)B * 2;
    if (lane < 16) outFeat[(size_t)b * 16 + lane] = f;
    if (lane < 2)  outg[(size_t)b * 2 + lane] = (lane == 0 ? t0 : t1) - lse;
  }
}

extern "C" void kernel_launch(void* const* d_in, const int* in_sizes, int n_in,
                              void* d_out, int out_size, void* d_ws, size_t ws_size,
                              hipStream_t stream) {
  const float* x  = (const float*)d_in[0];
  const float* w1 = (const float*)d_in[1];
  const float* w2 = (const float*)d_in[2];
  const float* w3 = (const float*)d_in[3];
  const float* fc = (const float*)d_in[4];
  float* out = (float*)d_out;
  int B = in_sizes[0] / 1024;
  int grid = (B + 3) / 4;
  hipLaunchKernelGGL(spd_fused, dim3(grid), dim3(256), 0, stream,
                     x, w1, w2, w3, fc, out, B);
}

// Round 21
// 1260.536 us; speedup vs baseline: 1.6436x; 1.1477x over previous
//
#include <hip/hip_runtime.h>

// Wave-level LDS ordering fence for the few remaining LDS phase transitions.
#define FENCE() asm volatile("s_waitcnt lgkmcnt(0)" ::: "memory")

typedef float v2f   __attribute__((ext_vector_type(2)));
typedef float f32x4 __attribute__((ext_vector_type(4)));

__device__ __forceinline__ float fshfl_xor(float v, int m) { return __shfl_xor(v, m, 64); }
__device__ __forceinline__ float fsqrt(float x) { return __builtin_amdgcn_sqrtf(x); }
__device__ __forceinline__ float frcp (float x) { return __builtin_amdgcn_rcpf(x); }
__device__ __forceinline__ float frsq (float x) { return __builtin_amdgcn_rsqf(x); }
__device__ __forceinline__ v2f   fma2(v2f a, v2f b, v2f c)       { return __builtin_elementwise_fma(a, b, c); }
__device__ __forceinline__ f32x4 fma4(f32x4 a, f32x4 b, f32x4 c) { return __builtin_elementwise_fma(a, b, c); }

// ---- VALU-pipe lane exchange (r18/r20, validated: dur 2030->1641->1447).
template<int C>
__device__ __forceinline__ float dppf(float x) {
  return __builtin_bit_cast(float,
      __builtin_amdgcn_mov_dpp(__builtin_bit_cast(int, x), C, 0xF, 0xF, true));
}
#define DPP_X1  0xB1   // quad_perm [1,0,3,2]
#define DPP_X2  0x4E   // quad_perm [2,3,0,1]
#define DPP_X3  0x1B   // quad_perm [3,2,1,0]
#define DPP_X7  0x141  // row_half_mirror
#define DPP_X15 0x140  // row_mirror

__device__ __forceinline__ float pl32_sum(float x) {
#if __has_builtin(__builtin_amdgcn_permlane32_swap)
  unsigned xi = __builtin_bit_cast(unsigned, x);
  auto r = __builtin_amdgcn_permlane32_swap(xi, xi, false, false);
  return __builtin_bit_cast(float, (unsigned)r[0]) +
         __builtin_bit_cast(float, (unsigned)r[1]);
#else
  return x + fshfl_xor(x, 32);
#endif
}
__device__ __forceinline__ float pl32_max(float x) {
#if __has_builtin(__builtin_amdgcn_permlane32_swap)
  unsigned xi = __builtin_bit_cast(unsigned, x);
  auto r = __builtin_amdgcn_permlane32_swap(xi, xi, false, false);
  return fmaxf(__builtin_bit_cast(float, (unsigned)r[0]),
               __builtin_bit_cast(float, (unsigned)r[1]));
#else
  return fmaxf(x, fshfl_xor(x, 32));
#endif
}
__device__ __forceinline__ float pl16_sum(float x) {
#if __has_builtin(__builtin_amdgcn_permlane16_swap)
  unsigned xi = __builtin_bit_cast(unsigned, x);
  auto r = __builtin_amdgcn_permlane16_swap(xi, xi, false, false);
  return __builtin_bit_cast(float, (unsigned)r[0]) +
         __builtin_bit_cast(float, (unsigned)r[1]);
#else
  return x + fshfl_xor(x, 16);
#endif
}
__device__ __forceinline__ float pl16_max(float x) {
#if __has_builtin(__builtin_amdgcn_permlane16_swap)
  unsigned xi = __builtin_bit_cast(unsigned, x);
  auto r = __builtin_amdgcn_permlane16_swap(xi, xi, false, false);
  return fmaxf(__builtin_bit_cast(float, (unsigned)r[0]),
               __builtin_bit_cast(float, (unsigned)r[1]));
#else
  return fmaxf(x, fshfl_xor(x, 16));
#endif
}
__device__ __forceinline__ float pl16_get(float x, int lane_) {
#if __has_builtin(__builtin_amdgcn_permlane16_swap)
  unsigned xi = __builtin_bit_cast(unsigned, x);
  auto r = __builtin_amdgcn_permlane16_swap(xi, xi, false, false);
  float a = __builtin_bit_cast(float, (unsigned)r[0]);
  float b = __builtin_bit_cast(float, (unsigned)r[1]);
  return (lane_ & 16) ? a : b;   // out0 holds x[i&~16], out1 holds x[i|16]
#else
  return fshfl_xor(x, 16);
#endif
}

// One block = 256 threads = 4 waves, one 32x32 SPD matrix per wave.
// r21 = r20 (VALU-bound at 86.7% busy; DS->VALU shift spent, occupancy axis
// dead) with a pure CONVERGENCE-BUDGET trim -- sweeps scale both pipes:
//  stage-1 cap 7->6, stage-2 5->4, stage-3 5->4 (quadratic convergence:
//  n=32 needs ~5-6 sweeps to rel~1e-5, n=16 ~4, 4x4 ~3);
//  skip threshold 1e-13 -> 1e-11 (just under the 1e-10 exit) so final-sweep
//  rounds where all pairs are converged take the execz all-skip fast path.
// 3x absmax headroom (0.25 vs 0.75, invariant across all precision changes)
// backs the trim; revert to r20 if absmax > ~0.5.
// Spill tripwire: WRITE_SIZE ~2.3MB. LDS: 4*1152*4 = 18432 B/block.
#define PT_S 34
__global__ __launch_bounds__(256) void spd_fused(
    const float* __restrict__ xg,
    const float* __restrict__ w1g,
    const float* __restrict__ w2g,
    const float* __restrict__ w3g,
    const float* __restrict__ fcg,
    float* __restrict__ outg,
    int B)
{
  __shared__ float slot[4][1152];

  const int tid  = threadIdx.x;
  const int wid  = tid >> 6;
  const int lane = tid & 63;

  float* Cc = slot[wid];          // x (stride 32) -> M1 cols (stride 36) -> Qb/J scratch
  float* Pt = slot[wid] + 576;    // Ps transposed [16][PT_S], in dead M1 space

  const long b = (long)blockIdx.x * 4 + wid;
  if (b >= B) return;

  // ---------------- load x -> Cc row-major [32][32] (stride 32)
  {
    const f32x4* xv = (const f32x4*)(xg + (size_t)b * 1024);
    f32x4* c4 = (f32x4*)Cc;
    #pragma unroll
    for (int jj = 0; jj < 4; ++jj) {
      int i4 = lane + 64 * jj;
      c4[i4] = xv[i4];
    }
  }
  FENCE();

  const int j = lane & 31;
  const int h = lane >> 5;

  // ---------------- Tmat = x * w1 in registers (packed). T2[e] = rows
  // {16h+2e, +1} of column j. Uses x symmetry: read x rows as f32x4.
  v2f T2[8];
  {
    #pragma unroll
    for (int e = 0; e < 8; ++e) T2[e] = (v2f){0.f, 0.f};
    const f32x4* c4 = (const f32x4*)Cc;
    #pragma unroll 4
    for (int c = 0; c < 32; ++c) {
      float wv = w1g[c * 32 + j];
      v2f wv2 = {wv, wv};
      f32x4 x0 = c4[c * 8 + h * 4 + 0];
      f32x4 x1 = c4[c * 8 + h * 4 + 1];
      f32x4 x2 = c4[c * 8 + h * 4 + 2];
      f32x4 x3 = c4[c * 8 + h * 4 + 3];
      T2[0] = fma2(x0.lo, wv2, T2[0]); T2[1] = fma2(x0.hi, wv2, T2[1]);
      T2[2] = fma2(x1.lo, wv2, T2[2]); T2[3] = fma2(x1.hi, wv2, T2[3]);
      T2[4] = fma2(x2.lo, wv2, T2[4]); T2[5] = fma2(x2.hi, wv2, T2[5]);
      T2[6] = fma2(x3.lo, wv2, T2[6]); T2[7] = fma2(x3.hi, wv2, T2[7]);
    }
  }
  FENCE();   // all x reads complete before M1 overwrites Cc

  // ---------------- M1 = w1^T * Tmat -> Cc linear column-major, stride 36.
  {
    const f32x4* w14 = (const f32x4*)w1g;   // row r = w14[r*8 + 0..7]
    #pragma unroll
    for (int ih2 = 0; ih2 < 4; ++ih2) {     // output rows 8*ih2 .. 8*ih2+7
      f32x4 A = {0.f, 0.f, 0.f, 0.f};
      f32x4 Bv = {0.f, 0.f, 0.f, 0.f};
      #pragma unroll
      for (int e = 0; e < 16; ++e) {
        int r = 16 * h + e;
        float tv = T2[e >> 1][e & 1];
        f32x4 tv4 = {tv, tv, tv, tv};
        A  = fma4(w14[r * 8 + ih2 * 2],     tv4, A);
        Bv = fma4(w14[r * 8 + ih2 * 2 + 1], tv4, Bv);
      }
      A.x = pl32_sum(A.x);  A.y = pl32_sum(A.y);
      A.z = pl32_sum(A.z);  A.w = pl32_sum(A.w);
      Bv.x = pl32_sum(Bv.x); Bv.y = pl32_sum(Bv.y);
      Bv.z = pl32_sum(Bv.z); Bv.w = pl32_sum(Bv.w);
      if (h == (ih2 & 1)) {
        *(f32x4*)(Cc + j * 36 + ih2 * 8)     = A;
        *(f32x4*)(Cc + j * 36 + ih2 * 8 + 4) = Bv;
      }
    }
  }
  FENCE();

  // ---------------- load own column half into v2f registers (one-time)
  v2f v1[8];
  {
    const float* bp = Cc + j * 36 + (h << 4);
    f32x4 q0 = *(const f32x4*)(bp);
    f32x4 q1 = *(const f32x4*)(bp + 4);
    f32x4 q2 = *(const f32x4*)(bp + 8);
    f32x4 q3 = *(const f32x4*)(bp + 12);
    v1[0] = q0.lo; v1[1] = q0.hi; v1[2] = q1.lo; v1[3] = q1.hi;
    v1[4] = q2.lo; v1[5] = q2.hi; v1[6] = q3.lo; v1[7] = q3.hi;
  }

  // ---------------- one-sided Jacobi, n=32, register-resident, XOR
  // tournament (peeled VALU rounds first), incremental norms.
  {
    #define S1ROUND(MVAL, GETF) do {                                       \
      const int m_ = j ^ (MVAL);                                           \
      v2f uu[8];                                                           \
      _Pragma("unroll") for (int i = 0; i < 8; ++i) {                      \
        uu[i].x = GETF(v1[i].x); uu[i].y = GETF(v1[i].y); }                \
      float sb_o = GETF(sn);                                               \
      v2f sgv = {0.f, 0.f};                                                \
      _Pragma("unroll") for (int i = 0; i < 8; ++i)                        \
        sgv = fma2(v1[i], uu[i], sgv);                                     \
      float sg = pl32_sum(sgv.x + sgv.y);                                  \
      const bool isp = j < m_;                                             \
      float nA = isp ? sn : sb_o;                                          \
      float nB = isp ? sb_o : sn;                                          \
      float rel = sg * sg * frcp(fmaxf(nA * nB, 1e-30f));                  \
      offmax = fmaxf(offmax, rel);                                         \
      if (rel > 1e-11f) {                                                  \
        float uc = 0.5f * (nB - nA);                                       \
        float R  = fsqrt(uc * uc + sg * sg);                               \
        float t  = sg * frcp(uc + ((uc >= 0.f) ? R : -R));                 \
        float ct = frsq(1.f + t * t);                                      \
        float st = ct * t;                                                 \
        float s_ = isp ? -st : st;                                         \
        v2f ct2 = {ct, ct}, sv2 = {s_, s_};                                \
        _Pragma("unroll") for (int i = 0; i < 8; ++i)                      \
          v1[i] = fma2(uu[i], sv2, v1[i] * ct2);                           \
        sn = fmaxf(isp ? (nA - t * sg) : (nB + t * sg), 0.f);              \
      }                                                                    \
    } while (0)
    #define G_D1(v)  dppf<DPP_X1>(v)
    #define G_D2(v)  dppf<DPP_X2>(v)
    #define G_D3(v)  dppf<DPP_X3>(v)
    #define G_D7(v)  dppf<DPP_X7>(v)
    #define G_D15(v) dppf<DPP_X15>(v)
    #define G_P16(v) pl16_get(v, lane)
    #define G_C17(v) pl16_get(dppf<DPP_X1>(v), lane)   // xor17 = xor1*xor16
    #define G_C18(v) pl16_get(dppf<DPP_X2>(v), lane)   // xor18 = xor2*xor16
    #define G_RT(v)  fshfl_xor(v, mask)

    #pragma unroll 1
    for (int sweep = 0; sweep < 6; ++sweep) {
      // fresh own-norm (kills incremental drift)
      v2f s2n = {0.f, 0.f};
      #pragma unroll
      for (int i = 0; i < 8; ++i) s2n = fma2(v1[i], v1[i], s2n);
      float sn = pl32_sum(s2n.x + s2n.y);

      float offmax = 0.f;
      // peeled VALU-pipe rounds (DPP / permlane / composed)
      S1ROUND(1,  G_D1);
      S1ROUND(2,  G_D2);
      S1ROUND(3,  G_D3);
      S1ROUND(7,  G_D7);
      S1ROUND(15, G_D15);
      S1ROUND(16, G_P16);
      S1ROUND(17, G_C17);
      S1ROUND(18, G_C18);
      // remaining masks on the DS pipe
      #pragma unroll 1
      for (int mask = 4; mask < 7; ++mask)   S1ROUND(mask, G_RT);
      #pragma unroll 1
      for (int mask = 8; mask < 15; ++mask)  S1ROUND(mask, G_RT);
      #pragma unroll 1
      for (int mask = 19; mask < 32; ++mask) S1ROUND(mask, G_RT);

      offmax = fmaxf(offmax, dppf<DPP_X1>(offmax));
      offmax = fmaxf(offmax, dppf<DPP_X2>(offmax));
      offmax = fmaxf(offmax, fshfl_xor(offmax, 4));
      offmax = fmaxf(offmax, fshfl_xor(offmax, 8));
      offmax = pl16_max(offmax);
      offmax = pl32_max(offmax);
      if (offmax < 1e-10f) break;
    }
  }

  // ---------------- lambda_1 + ReEig + Ps = sqrt(clamp(lam1))*v1hat^T w2,
  // all from registers; Pt[16][PT_S] transposed (conflict-free).
  // Split halves with sched_barrier: caps the w2-load hoisting spike.
  {
    v2f ssv = {0.f, 0.f};
    #pragma unroll
    for (int i = 0; i < 8; ++i) ssv = fma2(v1[i], v1[i], ssv);
    float ss = pl32_sum(ssv.x + ssv.y);
    float lam = fsqrt(ss);
    float sc1 = (lam > 0.f) ? (fsqrt(fmaxf(lam, 1e-4f)) * frcp(lam)) : 0.f;
    f32x4 acc0 = {0.f,0.f,0.f,0.f}, acc1 = acc0, acc2 = acc0, acc3 = acc0;
    #pragma unroll
    for (int t = 0; t < 4; ++t) {
      int rr = (h << 4) + 2 * t;
      const f32x4* wr0 = (const f32x4*)(w2g + rr * 16);
      const f32x4* wr1 = (const f32x4*)(w2g + (rr + 1) * 16);
      float vx = v1[t].x, vy = v1[t].y;
      f32x4 vx4 = {vx, vx, vx, vx};
      f32x4 vy4 = {vy, vy, vy, vy};
      acc0 = fma4(wr0[0], vx4, acc0); acc1 = fma4(wr0[1], vx4, acc1);
      acc2 = fma4(wr0[2], vx4, acc2); acc3 = fma4(wr0[3], vx4, acc3);
      acc0 = fma4(wr1[0], vy4, acc0); acc1 = fma4(wr1[1], vy4, acc1);
      acc2 = fma4(wr1[2], vy4, acc2); acc3 = fma4(wr1[3], vy4, acc3);
    }
    __builtin_amdgcn_sched_barrier(0);   // don't hoist 2nd-half loads above
    #pragma unroll
    for (int t = 4; t < 8; ++t) {
      int rr = (h << 4) + 2 * t;
      const f32x4* wr0 = (const f32x4*)(w2g + rr * 16);
      const f32x4* wr1 = (const f32x4*)(w2g + (rr + 1) * 16);
      float vx = v1[t].x, vy = v1[t].y;
      f32x4 vx4 = {vx, vx, vx, vx};
      f32x4 vy4 = {vy, vy, vy, vy};
      acc0 = fma4(wr0[0], vx4, acc0); acc1 = fma4(wr0[1], vx4, acc1);
      acc2 = fma4(wr0[2], vx4, acc2); acc3 = fma4(wr0[3], vx4, acc3);
      acc0 = fma4(wr1[0], vy4, acc0); acc1 = fma4(wr1[1], vy4, acc1);
      acc2 = fma4(wr1[2], vy4, acc2); acc3 = fma4(wr1[3], vy4, acc3);
    }
    acc0.x = pl32_sum(acc0.x) * sc1;  acc0.y = pl32_sum(acc0.y) * sc1;
    acc0.z = pl32_sum(acc0.z) * sc1;  acc0.w = pl32_sum(acc0.w) * sc1;
    acc1.x = pl32_sum(acc1.x) * sc1;  acc1.y = pl32_sum(acc1.y) * sc1;
    acc1.z = pl32_sum(acc1.z) * sc1;  acc1.w = pl32_sum(acc1.w) * sc1;
    acc2.x = pl32_sum(acc2.x) * sc1;  acc2.y = pl32_sum(acc2.y) * sc1;
    acc2.z = pl32_sum(acc2.z) * sc1;  acc2.w = pl32_sum(acc2.w) * sc1;
    acc3.x = pl32_sum(acc3.x) * sc1;  acc3.y = pl32_sum(acc3.y) * sc1;
    acc3.z = pl32_sum(acc3.z) * sc1;  acc3.w = pl32_sum(acc3.w) * sc1;
    // lane (j,h) stores Ps[j][8h..8h+7]: h=0 -> acc0/acc1, h=1 -> acc2/acc3
    f32x4 lo = h ? acc2 : acc0;
    f32x4 hi = h ? acc3 : acc1;
    const int jb8 = h << 3;
    Pt[(jb8 + 0) * PT_S + j] = lo.x;
    Pt[(jb8 + 1) * PT_S + j] = lo.y;
    Pt[(jb8 + 2) * PT_S + j] = lo.z;
    Pt[(jb8 + 3) * PT_S + j] = lo.w;
    Pt[(jb8 + 4) * PT_S + j] = hi.x;
    Pt[(jb8 + 5) * PT_S + j] = hi.y;
    Pt[(jb8 + 6) * PT_S + j] = hi.z;
    Pt[(jb8 + 7) * PT_S + j] = hi.w;
  }
  FENCE();

  // ---------------- M2 = Ps^T Ps directly into stage-2 registers.
  // lane = c2 + 16*h4 owns rows 4h4..4h4+3 of M2 column c2.
  const int c2 = lane & 15;
  const int h4 = lane >> 4;
  f32x4 v2r;
  {
    v2f a0 = {0.f,0.f}, a1 = {0.f,0.f}, a2 = {0.f,0.f}, a3 = {0.f,0.f};
    #pragma unroll 2
    for (int kk = 0; kk < 32; kk += 4) {
      f32x4 aa = *(const f32x4*)(Pt + c2 * PT_S + kk);
      f32x4 b0 = *(const f32x4*)(Pt + (4 * h4 + 0) * PT_S + kk);
      f32x4 b1 = *(const f32x4*)(Pt + (4 * h4 + 1) * PT_S + kk);
      f32x4 b2 = *(const f32x4*)(Pt + (4 * h4 + 2) * PT_S + kk);
      f32x4 b3 = *(const f32x4*)(Pt + (4 * h4 + 3) * PT_S + kk);
      a0 = fma2(aa.lo, b0.lo, a0); a0 = fma2(aa.hi, b0.hi, a0);
      a1 = fma2(aa.lo, b1.lo, a1); a1 = fma2(aa.hi, b1.hi, a1);
      a2 = fma2(aa.lo, b2.lo, a2); a2 = fma2(aa.hi, b2.hi, a2);
      a3 = fma2(aa.lo, b3.lo, a3); a3 = fma2(aa.hi, b3.hi, a3);
    }
    v2r.x = a0.x + a0.y;
    v2r.y = a1.x + a1.y;
    v2r.z = a2.x + a2.y;
    v2r.w = a3.x + a3.y;
  }

  // ---------------- one-sided Jacobi, n=16, register-resident, XOR
  // tournament (peeled DPP rounds), incremental norms.
  {
    #define S2ROUND(MVAL, GETF) do {                                       \
      const int m_ = c2 ^ (MVAL);                                          \
      float u0 = GETF(v2r.x), u1 = GETF(v2r.y);                            \
      float u2 = GETF(v2r.z), u3 = GETF(v2r.w);                            \
      float sb_o = GETF(sn2);                                              \
      v2f ua = {u0, u1}, ub = {u2, u3};                                    \
      v2f sgv = fma2(v2r.hi, ub, v2r.lo * ua);                             \
      float sg = pl32_sum(pl16_sum(sgv.x + sgv.y));                        \
      const bool isp = c2 < m_;                                            \
      float nA = isp ? sn2 : sb_o;                                         \
      float nB = isp ? sb_o : sn2;                                         \
      float rel = sg * sg * frcp(fmaxf(nA * nB, 1e-30f));                  \
      offmax = fmaxf(offmax, rel);                                         \
      if (rel > 1e-11f) {                                                  \
        float uc = 0.5f * (nB - nA);                                       \
        float R  = fsqrt(uc * uc + sg * sg);                               \
        float t  = sg * frcp(uc + ((uc >= 0.f) ? R : -R));                 \
        float ct = frsq(1.f + t * t);                                      \
        float st = ct * t;                                                 \
        float s_ = isp ? -st : st;                                         \
        f32x4 ct4 = {ct, ct, ct, ct};                                      \
        f32x4 s4  = {s_, s_, s_, s_};                                      \
        f32x4 uu4 = {u0, u1, u2, u3};                                      \
        v2r = fma4(uu4, s4, v2r * ct4);                                    \
        sn2 = fmaxf(isp ? (nA - t * sg) : (nB + t * sg), 0.f);             \
      }                                                                    \
    } while (0)

    #pragma unroll 1
    for (int sweep = 0; sweep < 4; ++sweep) {
      v2f sp = fma2(v2r.hi, v2r.hi, v2r.lo * v2r.lo);
      float sn2 = pl32_sum(pl16_sum(sp.x + sp.y));
      float offmax = 0.f;
      S2ROUND(1,  G_D1);
      S2ROUND(2,  G_D2);
      S2ROUND(3,  G_D3);
      S2ROUND(7,  G_D7);
      S2ROUND(15, G_D15);
      #pragma unroll 1
      for (int mask = 4; mask < 7; ++mask)  S2ROUND(mask, G_RT);
      #pragma unroll 1
      for (int mask = 8; mask < 15; ++mask) S2ROUND(mask, G_RT);

      offmax = fmaxf(offmax, dppf<DPP_X1>(offmax));
      offmax = fmaxf(offmax, dppf<DPP_X2>(offmax));
      offmax = fmaxf(offmax, fshfl_xor(offmax, 4));
      offmax = fmaxf(offmax, fshfl_xor(offmax, 8));
      offmax = pl16_max(offmax);
      offmax = pl32_max(offmax);
      if (offmax < 1e-10f) break;
    }
  }

  // ---------------- Qb row c2 = (V2^T w3)[c2][:] * sqrt(clamp(lam2)) from regs
  {
    f32x4 qq = {0.f, 0.f, 0.f, 0.f};
    f32x4 w0 = *(const f32x4*)(w3g + (4 * h4 + 0) * 4);
    f32x4 w1r = *(const f32x4*)(w3g + (4 * h4 + 1) * 4);
    f32x4 w2r = *(const f32x4*)(w3g + (4 * h4 + 2) * 4);
    f32x4 w3r = *(const f32x4*)(w3g + (4 * h4 + 3) * 4);
    f32x4 vv0 = {v2r.x, v2r.x, v2r.x, v2r.x};
    f32x4 vv1 = {v2r.y, v2r.y, v2r.y, v2r.y};
    f32x4 vv2 = {v2r.z, v2r.z, v2r.z, v2r.z};
    f32x4 vv3 = {v2r.w, v2r.w, v2r.w, v2r.w};
    qq = fma4(w0, vv0, qq); qq = fma4(w1r, vv1, qq);
    qq = fma4(w2r, vv2, qq); qq = fma4(w3r, vv3, qq);
    v2f sp = fma2(v2r.hi, v2r.hi, v2r.lo * v2r.lo);
    float ssp = sp.x + sp.y;
    float q0 = pl32_sum(pl16_sum(qq.x));
    float q1 = pl32_sum(pl16_sum(qq.y));
    float q2 = pl32_sum(pl16_sum(qq.z));
    float q3 = pl32_sum(pl16_sum(qq.w));
    ssp = pl32_sum(pl16_sum(ssp));
    float lam = fsqrt(ssp);
    float scl = (lam > 0.f) ? (frcp(lam) * fsqrt(fmaxf(lam, 1e-4f))) : 0.f;
    if (h4 == 0)
      *(f32x4*)(Cc + c2 * 4) = (f32x4){q0 * scl, q1 * scl, q2 * scl, q3 * scl};
  }
  FENCE();

  // ---------------- stage 3: one-sided Jacobi ON THE 16x4 FACTOR, with
  // accumulated rotations J (eigenvectors of M3 = Q^T Q). 4 sweeps.
  float qv = Cc[lane];            // Qb[kq][jq], kq*4+jq == lane
  const int kq = lane >> 2;
  const int jq = lane & 3;
  float jv = (kq == jq) ? 1.f : 0.f;
  {
    #define ROT3(P_, Q_, DC_) do {                                        \
      float w_ = dppf<DC_>(qv);                                           \
      float s1 = qv * qv, s2 = w_ * w_, s3 = qv * w_;                     \
      s1 += fshfl_xor(s1, 4);  s2 += fshfl_xor(s2, 4);  s3 += fshfl_xor(s3, 4); \
      s1 += fshfl_xor(s1, 8);  s2 += fshfl_xor(s2, 8);  s3 += fshfl_xor(s3, 8); \
      s1 = pl16_sum(s1); s2 = pl16_sum(s2); s3 = pl16_sum(s3);            \
      s1 = pl32_sum(s1); s2 = pl32_sum(s2); s3 = pl32_sum(s3);            \
      bool isp = (jq == (P_)), isq = (jq == (Q_));                        \
      float sa = isp ? s1 : s2;                                           \
      float sb = isp ? s2 : s1;                                           \
      float u_ = 0.5f * (sb - sa);                                        \
      float R_ = fsqrt(u_ * u_ + s3 * s3);                                \
      float dn_ = u_ + copysignf(fmaxf(R_, 1e-30f), u_);                  \
      float t_ = s3 * frcp(dn_);                                          \
      float ct = frsq(1.f + t_ * t_);                                     \
      float st = ct * t_;                                                 \
      float wj_ = dppf<DC_>(jv);                                          \
      float nv  = isp ? (ct * qv - st * w_)  : (st * w_  + ct * qv);      \
      float nvj = isp ? (ct * jv - st * wj_) : (st * wj_ + ct * jv);      \
      if (isp | isq) { qv = nv; jv = nvj; }                               \
    } while (0)

    #pragma unroll 1
    for (int sweep = 0; sweep < 4; ++sweep) {
      ROT3(0,1,DPP_X1); ROT3(2,3,DPP_X1);
      ROT3(0,2,DPP_X2); ROT3(1,3,DPP_X2);
      ROT3(0,3,DPP_X3); ROT3(1,2,DPP_X3);
    }
    #undef ROT3
  }

  // ---------------- lambda_3 = ||col||^2, LogEig via J, FC, log_softmax
  {
    float ss = qv * qv;
    ss += fshfl_xor(ss, 4); ss += fshfl_xor(ss, 8);
    ss = pl16_sum(ss); ss = pl32_sum(ss);
    float lwv = logf(fmaxf(ss, 1e-10f));       // log eigenvalue of column jq
    if (kq < 4)  Cc[64 + kq * 4 + jq] = jv;    // J, row-major 4x4
    if (kq == 0) Cc[80 + jq] = lwv;            // lanes 0..3: per-column loglam
    FENCE();

    float f = 0.f;
    if (lane < 16) {
      int i3 = lane >> 2, j3 = lane & 3;
      #pragma unroll
      for (int c = 0; c < 4; ++c)
        f += Cc[80 + c] * Cc[64 + i3 * 4 + c] * Cc[64 + j3 * 4 + c];
    }
    float t0 = 0.f, t1 = 0.f;
    if (lane < 16) { t0 = f * fcg[2 * lane]; t1 = f * fcg[2 * lane + 1]; }
    t0 += dppf<DPP_X1>(t0); t1 += dppf<DPP_X1>(t1);
    t0 += dppf<DPP_X2>(t0); t1 += dppf<DPP_X2>(t1);
    t0 += fshfl_xor(t0, 4); t1 += fshfl_xor(t1, 4);
    t0 += fshfl_xor(t0, 8); t1 += fshfl_xor(t1, 8);
    float mx  = fmaxf(t0, t1);
    float lse = mx + logf(expf(t0 - mx) + expf(t1 - mx));

    float* outFeat = outg + (size_t)B * 2;
    if (lane < 16) outFeat[(size_t)b * 16 + lane] = f;
    if (lane < 2)  outg[(size_t)b * 2 + lane] = (lane == 0 ? t0 : t1) - lse;
  }
}

extern "C" void kernel_launch(void* const* d_in, const int* in_sizes, int n_in,
                              void* d_out, int out_size, void* d_ws, size_t ws_size,
                              hipStream_t stream) {
  const float* x  = (const float*)d_in[0];
  const float* w1 = (const float*)d_in[1];
  const float* w2 = (const float*)d_in[2];
  const float* w3 = (const float*)d_in[3];
  const float* fc = (const float*)d_in[4];
  float* out = (float*)d_out;
  int B = in_sizes[0] / 1024;
  int grid = (B + 3) / 4;
  hipLaunchKernelGGL(spd_fused, dim3(grid), dim3(256), 0, stream,
                     x, w1, w2, w3, fc, out, B);
}